// Round 12
// baseline (1398.430 us; speedup 1.0000x reference)
//
#include <hip/hip_runtime.h>
#include <cstdint>

#define NB 16
#define NN 4096
#define ND 64
#define NPOINT 1024
#define NSAMPLE 32
#define NROWS (NB * NPOINT * NSAMPLE)   // 524288 rows through the MLP
#define BN_EPS 1e-5f
#define NSLOT 32
#define LD 68                            // LDS tile leading dim (rows+pad)

// ---------------- ws layout (bytes) ----------------
#define OFF_GIDX   0
#define OFF_STATS  (2 * 1024 * 1024)
#define OFF_MAX    (OFF_STATS + 131072)
#define OFF_MIN    (OFF_MAX + 8388608)
#define MED_TOTAL  ((size_t)OFF_MIN + 8388608)       // ~18.1 MB
#define SMALL_TOTAL ((size_t)OFF_MAX)                // ~2.1 MB
#define OFF_Y2BF   MED_TOTAL                         // bf16 y2: 64 MB
#define BIG_TOTAL  (OFF_Y2BF + (size_t)NROWS * 64 * 2)    // ~82.1 MB
#define OFF_Y1BF   BIG_TOTAL                         // bf16 y1: 64 MB
#define BIG2_TOTAL (OFF_Y1BF + (size_t)NROWS * 64 * 2)    // ~146.2 MB

// stats area float offsets
#define S1SUM 0
#define S1SQ  2048
#define S2SUM 4096
#define S2SQ  6144
#define S3SUM 8192
#define S3SQ  12288
#define A3OFF 16384
#define C3OFF 16512

__device__ __forceinline__ unsigned short f2bf(float f) {
    const unsigned u = __float_as_uint(f);
    return (unsigned short)((u + 0x7FFFu + ((u >> 16) & 1u)) >> 16);   // RNE
}
__device__ __forceinline__ float bf2f(unsigned short s) {
    return __uint_as_float(((unsigned)s) << 16);
}

// =====================================================================
// K1: farthest point sampling. One block (512 thr = 8 waves) per batch.
// CONTIGUOUS 8 pts/lane (lane order == index order), f32-value-only
// butterfly + ballot/ctz index recovery, float4 per-wave slots carrying
// the candidate xyz. One barrier/iter (parity slots). Exact np
// arithmetic; first-index tie-break preserved by construction:
//  - within lane: ascending k, strict >
//  - within wave: lowest tied lane (= smallest index, contiguity)
//  - across waves: sequential slot scan, strict > (lowest wave wins)
// =====================================================================
__global__ __launch_bounds__(512) void fps_kernel(const float* __restrict__ xyz,
                                                  float* __restrict__ out_newxyz) {
    __shared__ float pxyz[NN * 3];      // 48 KB
    __shared__ float4 slot[2][8];       // {val, x, y, z} per wave, parity-buffered
    const int b = blockIdx.x, tid = threadIdx.x;
    const int wave = tid >> 6, lane = tid & 63;
    const float* base = xyz + (size_t)b * NN * 3;

    for (int i = tid; i < NN * 3 / 4; i += 512)
        reinterpret_cast<float4*>(pxyz)[i] = reinterpret_cast<const float4*>(base)[i];
    __syncthreads();

    // registers: lane tid holds points p = tid*8 + k (contiguous)
    float X[8], Y[8], Z[8], D[8];
#pragma unroll
    for (int k = 0; k < 8; ++k) {
        const int p = tid * 8 + k;
        X[k] = pxyz[3 * p + 0];
        Y[k] = pxyz[3 * p + 1];
        Z[k] = pxyz[3 * p + 2];
        D[k] = 1e10f;
    }

    float cx = pxyz[0], cy = pxyz[1], cz = pxyz[2];   // initial farthest = 0
    float* outb = out_newxyz + (size_t)b * NPOINT * 3;

    for (int it = 0; it < NPOINT; ++it) {
        if (tid == 0) {
            outb[it * 3 + 0] = cx;
            outb[it * 3 + 1] = cy;
            outb[it * 3 + 2] = cz;
        }
        float bv = -1.0f;
        int   bi = 0;
#pragma unroll
        for (int k = 0; k < 8; ++k) {
            const float dx = __fsub_rn(X[k], cx);
            const float dy = __fsub_rn(Y[k], cy);
            const float dz = __fsub_rn(Z[k], cz);
            const float d  = __fadd_rn(__fadd_rn(__fmul_rn(dx, dx), __fmul_rn(dy, dy)),
                                       __fmul_rn(dz, dz));
            const float nd = fminf(D[k], d);
            D[k] = nd;
            if (nd > bv) { bv = nd; bi = tid * 8 + k; }  // strict > keeps smallest idx in-lane
        }
        const float lv = bv;   // local best before butterfly
        // wave-wide f32 max butterfly (value only)
#pragma unroll
        for (int off = 32; off >= 1; off >>= 1)
            bv = fmaxf(bv, __shfl_xor(bv, off));
        // lowest lane holding the max = smallest global index (contiguity)
        const unsigned long long mask = __ballot(lv == bv);
        const int src  = (int)__builtin_ctzll(mask);
        const int widx = __shfl(bi, src);
        const int par = it & 1;
        if (lane == 0) {
            slot[par][wave] = make_float4(bv, pxyz[3 * widx + 0],
                                              pxyz[3 * widx + 1],
                                              pxyz[3 * widx + 2]);
        }
        __syncthreads();
        float4 best = slot[par][0];
#pragma unroll
        for (int w = 1; w < 8; ++w) {
            const float4 s = slot[par][w];
            if (s.x > best.x) best = s;   // strict > : lowest wave wins ties
        }
        cx = best.y; cy = best.z; cz = best.w;
    }
}

// =====================================================================
// K2: query_ball_point. One wave per query; ordered prefix selection of
// first NSAMPLE idx with d^2 <= r^2. 2 chunks (128 pts) per loop iter.
// =====================================================================
__global__ __launch_bounds__(256) void query_kernel(const float* __restrict__ xyz,
                                                    const float* __restrict__ newxyz,
                                                    int* __restrict__ gidx) {
    const int gtid = blockIdx.x * 256 + threadIdx.x;
    const int q    = gtid >> 6;
    const int lane = threadIdx.x & 63;
    if (q >= NB * NPOINT) return;
    const int b = q >> 10;
    const float* xb = xyz + (size_t)b * NN * 3;
    const float cx = newxyz[q * 3 + 0];
    const float cy = newxyz[q * 3 + 1];
    const float cz = newxyz[q * 3 + 2];
    const float snew = __fadd_rn(__fadd_rn(__fmul_rn(cx, cx), __fmul_rn(cy, cy)),
                                 __fmul_rn(cz, cz));
    const float rsq = (float)(0.2 * 0.2);
    int* outq = gidx + (size_t)q * NSAMPLE;

    int count = 0, first = 0;
    for (int base = 0; base < NN; base += 128) {
        const int pA = base + lane, pB = base + 64 + lane;
        const float xA = xb[pA * 3 + 0], yA = xb[pA * 3 + 1], zA = xb[pA * 3 + 2];
        const float xB = xb[pB * 3 + 0], yB = xb[pB * 3 + 1], zB = xb[pB * 3 + 2];
        const float sxA = __fadd_rn(__fadd_rn(__fmul_rn(xA, xA), __fmul_rn(yA, yA)),
                                    __fmul_rn(zA, zA));
        const float sxB = __fadd_rn(__fadd_rn(__fmul_rn(xB, xB), __fmul_rn(yB, yB)),
                                    __fmul_rn(zB, zB));
        float dotA = __fmul_rn(cx, xA);
        dotA = fmaf(cy, yA, dotA);
        dotA = fmaf(cz, zA, dotA);
        float dotB = __fmul_rn(cx, xB);
        dotB = fmaf(cy, yB, dotB);
        dotB = fmaf(cz, zB, dotB);
        const float sqA = __fadd_rn(__fsub_rn(snew, __fadd_rn(dotA, dotA)), sxA);
        const float sqB = __fadd_rn(__fsub_rn(snew, __fadd_rn(dotB, dotB)), sxB);
        const bool qualA = !(sqA > rsq);
        const bool qualB = !(sqB > rsq);
        const unsigned long long maskA = __ballot(qualA);
        const unsigned long long maskB = __ballot(qualB);
        if (count == 0) {
            if (maskA)      first = base + (int)__builtin_ctzll(maskA);
            else if (maskB) first = base + 64 + (int)__builtin_ctzll(maskB);
        }
        const unsigned long long below = (1ull << lane) - 1ull;
        const int cA = __popcll(maskA);
        if (qualA) {
            const int pos = count + __popcll(maskA & below);
            if (pos < NSAMPLE) outq[pos] = pA;
        }
        if (qualB) {
            const int pos = count + cA + __popcll(maskB & below);
            if (pos < NSAMPLE) outq[pos] = pB;
        }
        count += cA + __popcll(maskB);
        if (count >= NSAMPLE) break;
    }
    if (count < NSAMPLE) {
        for (int pos = count + lane; pos < NSAMPLE; pos += 64) outq[pos] = first;
    }
}

// =====================================================================
// Shared device helpers for the 64-row tiled MLP passes.
// =====================================================================
__device__ __forceinline__ void stage64(const float* __restrict__ xyz,
                                        const float* __restrict__ points,
                                        const float* __restrict__ newxyz,
                                        const int* __restrict__ gidx,
                                        int row0, int tid, float* featT) {
    const int rl = tid >> 2, qd = tid & 3;
    const int R   = row0 + rl;
    const int grp = R >> 5;
    const int idx = gidx[R];
    const int b   = grp >> 10;
    const float* prow = points + ((size_t)b * NN + idx) * ND + qd * 16;
#pragma unroll
    for (int j = 0; j < 4; ++j) {
        const float4 v = *reinterpret_cast<const float4*>(prow + j * 4);
        const int k = 3 + qd * 16 + j * 4;
        featT[(k + 0) * LD + rl] = v.x;
        featT[(k + 1) * LD + rl] = v.y;
        featT[(k + 2) * LD + rl] = v.z;
        featT[(k + 3) * LD + rl] = v.w;
    }
    if (qd == 0) {
        const float* xr = xyz + ((size_t)b * NN + idx) * 3;
        const float* cr = newxyz + (size_t)grp * 3;
        featT[0 * LD + rl] = xr[0] - cr[0];
        featT[1 * LD + rl] = xr[1] - cr[1];
        featT[2 * LD + rl] = xr[2] - cr[2];
    }
}

__device__ __forceinline__ void fold64(const float* __restrict__ ssum,
                                       const float* __restrict__ ssq,
                                       const float* __restrict__ g,
                                       const float* __restrict__ bt,
                                       int tid, float* a_s, float* c_s) {
    if (tid < 64) {
        float s = 0.f, q = 0.f;
#pragma unroll
        for (int sl = 0; sl < NSLOT; ++sl) { s += ssum[sl * 64 + tid]; q += ssq[sl * 64 + tid]; }
        const float Ninv = 1.0f / (float)NROWS;
        const float mean = s * Ninv;
        const float var  = fmaf(-mean, mean, q * Ninv);
        const float a    = g[tid] * rsqrtf(var + BN_EPS);
        a_s[tid] = a;
        c_s[tid] = bt[tid] - mean * a;
    }
}

// y = inT @ w^T + b; out = relu(a*y + c), written transposed [64ch][LD]
template<int CIN>
__device__ __forceinline__ void mm_bnrelu(const float* __restrict__ w,
                                          const float* __restrict__ bias,
                                          const float* inT, float* outT,
                                          const float* a_s, const float* c_s, int tid) {
    const int c = tid & 63, rg = tid >> 6;
    float wr[CIN];
#pragma unroll
    for (int k = 0; k < CIN; ++k) wr[k] = w[c * CIN + k];
    const float bv = bias[c];
    const float av = a_s[c], cv = c_s[c];
#pragma unroll
    for (int bat = 0; bat < 2; ++bat) {
        const int rb = rg * 16 + bat * 8;
        float acc[8];
#pragma unroll
        for (int j = 0; j < 8; ++j) acc[j] = bv;
#pragma unroll
        for (int k = 0; k < CIN; ++k) {
            float f[8];
            *reinterpret_cast<float4*>(&f[0]) = *reinterpret_cast<const float4*>(&inT[k * LD + rb]);
            *reinterpret_cast<float4*>(&f[4]) = *reinterpret_cast<const float4*>(&inT[k * LD + rb + 4]);
            const float wv = wr[k];
#pragma unroll
            for (int j = 0; j < 8; ++j) acc[j] = fmaf(f[j], wv, acc[j]);
        }
        float o[8];
#pragma unroll
        for (int j = 0; j < 8; ++j) o[j] = fmaxf(0.f, fmaf(av, acc[j], cv));
        *reinterpret_cast<float4*>(&outT[c * LD + rb])     = *reinterpret_cast<float4*>(&o[0]);
        *reinterpret_cast<float4*>(&outT[c * LD + rb + 4]) = *reinterpret_cast<float4*>(&o[4]);
    }
}

// =====================================================================
// P1: stats for layer1 (Σy1, Σy1²). If ST, store raw y1 (pre-BN) bf16.
// =====================================================================
template<bool ST>
__global__ __launch_bounds__(256) void pass1_kernel(
    const float* __restrict__ xyz, const float* __restrict__ points,
    const float* __restrict__ newxyz, const int* __restrict__ gidx,
    const float* __restrict__ w1, const float* __restrict__ b1,
    float* __restrict__ stats, unsigned short* __restrict__ y1bf) {
    __shared__ float featT[67 * LD];
    __shared__ float red[4][64], redq[4][64];
    const int tid = threadIdx.x, blk = blockIdx.x;
    stage64(xyz, points, newxyz, gidx, blk * 64, tid, featT);
    __syncthreads();
    const int c = tid & 63, rg = tid >> 6;
    float wr[67];
#pragma unroll
    for (int k = 0; k < 67; ++k) wr[k] = w1[c * 67 + k];
    const float bv = b1[c];
    float ssum = 0.f, ssq = 0.f;
#pragma unroll
    for (int bat = 0; bat < 2; ++bat) {
        const int rb = rg * 16 + bat * 8;
        float acc[8];
#pragma unroll
        for (int j = 0; j < 8; ++j) acc[j] = bv;
#pragma unroll
        for (int k = 0; k < 67; ++k) {
            float f[8];
            *reinterpret_cast<float4*>(&f[0]) = *reinterpret_cast<const float4*>(&featT[k * LD + rb]);
            *reinterpret_cast<float4*>(&f[4]) = *reinterpret_cast<const float4*>(&featT[k * LD + rb + 4]);
            const float wv = wr[k];
#pragma unroll
            for (int j = 0; j < 8; ++j) acc[j] = fmaf(f[j], wv, acc[j]);
        }
        if (ST) {
            unsigned short o[8];
#pragma unroll
            for (int j = 0; j < 8; ++j) o[j] = f2bf(acc[j]);
            *reinterpret_cast<uint4*>(&y1bf[(size_t)blk * 4096 + c * 64 + rb]) =
                *reinterpret_cast<uint4*>(o);
        }
#pragma unroll
        for (int j = 0; j < 8; ++j) { ssum += acc[j]; ssq = fmaf(acc[j], acc[j], ssq); }
    }
    red[rg][c] = ssum;
    redq[rg][c] = ssq;
    __syncthreads();
    if (tid < 64) {
        const float s = red[0][tid] + red[1][tid] + red[2][tid] + red[3][tid];
        const float q = redq[0][tid] + redq[1][tid] + redq[2][tid] + redq[3][tid];
        const int slot = blk & (NSLOT - 1);
        atomicAdd(&stats[S1SUM + slot * 64 + tid], s);
        atomicAdd(&stats[S1SQ + slot * 64 + tid], q);
    }
}

// =====================================================================
// P2big: load bf16 y1 tile, t1 = relu(bn1(y1)), y2 matmul, store y2 bf16
// + stats2. No gather, no layer-1 recompute.
// =====================================================================
__global__ __launch_bounds__(256) void pass2big_kernel(
    const unsigned short* __restrict__ y1bf,
    const float* __restrict__ g1, const float* __restrict__ bt1,
    const float* __restrict__ w2, const float* __restrict__ b2,
    float* __restrict__ stats, unsigned short* __restrict__ y2bf) {
    __shared__ float t1T[64 * LD];
    __shared__ float a1s[64], c1s[64];
    __shared__ float red[4][64], redq[4][64];
    const int tid = threadIdx.x, blk = blockIdx.x;
    fold64(stats + S1SUM, stats + S1SQ, g1, bt1, tid, a1s, c1s);
    __syncthreads();
    {
        const int cch = tid >> 2, r0 = (tid & 3) * 16;
        const float a1 = a1s[cch], c1 = c1s[cch];
        const uint4 u0 = *reinterpret_cast<const uint4*>(&y1bf[(size_t)blk * 4096 + cch * 64 + r0]);
        const uint4 u1 = *reinterpret_cast<const uint4*>(&y1bf[(size_t)blk * 4096 + cch * 64 + r0 + 8]);
        const unsigned short* us0 = reinterpret_cast<const unsigned short*>(&u0);
        const unsigned short* us1 = reinterpret_cast<const unsigned short*>(&u1);
#pragma unroll
        for (int j = 0; j < 8; ++j) {
            t1T[cch * LD + r0 + j]     = fmaxf(0.f, fmaf(a1, bf2f(us0[j]), c1));
            t1T[cch * LD + r0 + 8 + j] = fmaxf(0.f, fmaf(a1, bf2f(us1[j]), c1));
        }
    }
    __syncthreads();
    const int c = tid & 63, rg = tid >> 6;
    float wr[64];
#pragma unroll
    for (int k = 0; k < 64; ++k) wr[k] = w2[c * 64 + k];
    const float bv = b2[c];
    float ssum = 0.f, ssq = 0.f;
#pragma unroll
    for (int bat = 0; bat < 2; ++bat) {
        const int rb = rg * 16 + bat * 8;
        float acc[8];
#pragma unroll
        for (int j = 0; j < 8; ++j) acc[j] = bv;
#pragma unroll
        for (int k = 0; k < 64; ++k) {
            float f[8];
            *reinterpret_cast<float4*>(&f[0]) = *reinterpret_cast<const float4*>(&t1T[k * LD + rb]);
            *reinterpret_cast<float4*>(&f[4]) = *reinterpret_cast<const float4*>(&t1T[k * LD + rb + 4]);
            const float wv = wr[k];
#pragma unroll
            for (int j = 0; j < 8; ++j) acc[j] = fmaf(f[j], wv, acc[j]);
        }
        {
            unsigned short o[8];
#pragma unroll
            for (int j = 0; j < 8; ++j) o[j] = f2bf(acc[j]);
            *reinterpret_cast<uint4*>(&y2bf[(size_t)blk * 4096 + c * 64 + rb]) =
                *reinterpret_cast<uint4*>(o);
        }
#pragma unroll
        for (int j = 0; j < 8; ++j) { ssum += acc[j]; ssq = fmaf(acc[j], acc[j], ssq); }
    }
    red[rg][c] = ssum;
    redq[rg][c] = ssq;
    __syncthreads();
    if (tid < 64) {
        const float s = red[0][tid] + red[1][tid] + red[2][tid] + red[3][tid];
        const float q = redq[0][tid] + redq[1][tid] + redq[2][tid] + redq[3][tid];
        const int slot = blk & (NSLOT - 1);
        atomicAdd(&stats[S2SUM + slot * 64 + tid], s);
        atomicAdd(&stats[S2SQ + slot * 64 + tid], q);
    }
}

// =====================================================================
// P2: full recompute variant. If ST stores y2 bf16.
// =====================================================================
template<bool ST>
__global__ __launch_bounds__(256) void pass2_kernel(
    const float* __restrict__ xyz, const float* __restrict__ points,
    const float* __restrict__ newxyz, const int* __restrict__ gidx,
    const float* __restrict__ w1, const float* __restrict__ b1,
    const float* __restrict__ g1, const float* __restrict__ bt1,
    const float* __restrict__ w2, const float* __restrict__ b2,
    float* __restrict__ stats, unsigned short* __restrict__ y2bf) {
    __shared__ float featT[67 * LD];
    __shared__ float t1T[64 * LD];
    __shared__ float a1s[64], c1s[64];
    __shared__ float red[4][64], redq[4][64];
    const int tid = threadIdx.x, blk = blockIdx.x;
    fold64(stats + S1SUM, stats + S1SQ, g1, bt1, tid, a1s, c1s);
    stage64(xyz, points, newxyz, gidx, blk * 64, tid, featT);
    __syncthreads();
    mm_bnrelu<67>(w1, b1, featT, t1T, a1s, c1s, tid);
    __syncthreads();
    const int c = tid & 63, rg = tid >> 6;
    float wr[64];
#pragma unroll
    for (int k = 0; k < 64; ++k) wr[k] = w2[c * 64 + k];
    const float bv = b2[c];
    float ssum = 0.f, ssq = 0.f;
#pragma unroll
    for (int bat = 0; bat < 2; ++bat) {
        const int rb = rg * 16 + bat * 8;
        float acc[8];
#pragma unroll
        for (int j = 0; j < 8; ++j) acc[j] = bv;
#pragma unroll
        for (int k = 0; k < 64; ++k) {
            float f[8];
            *reinterpret_cast<float4*>(&f[0]) = *reinterpret_cast<const float4*>(&t1T[k * LD + rb]);
            *reinterpret_cast<float4*>(&f[4]) = *reinterpret_cast<const float4*>(&t1T[k * LD + rb + 4]);
            const float wv = wr[k];
#pragma unroll
            for (int j = 0; j < 8; ++j) acc[j] = fmaf(f[j], wv, acc[j]);
        }
        if (ST) {
            unsigned short o[8];
#pragma unroll
            for (int j = 0; j < 8; ++j) o[j] = f2bf(acc[j]);
            *reinterpret_cast<uint4*>(&y2bf[(size_t)blk * 4096 + c * 64 + rb]) =
                *reinterpret_cast<uint4*>(o);
        }
#pragma unroll
        for (int j = 0; j < 8; ++j) { ssum += acc[j]; ssq = fmaf(acc[j], acc[j], ssq); }
    }
    red[rg][c] = ssum;
    redq[rg][c] = ssq;
    __syncthreads();
    if (tid < 64) {
        const float s = red[0][tid] + red[1][tid] + red[2][tid] + red[3][tid];
        const float q = redq[0][tid] + redq[1][tid] + redq[2][tid] + redq[3][tid];
        const int slot = blk & (NSLOT - 1);
        atomicAdd(&stats[S2SUM + slot * 64 + tid], s);
        atomicAdd(&stats[S2SQ + slot * 64 + tid], q);
    }
}

// =====================================================================
// P3big: load bf16 y2 tile, t2 = relu(bn2(y2)), y3 matmul (2-ch blocked),
// stats3 + per-(b,s,c) max/min.
// =====================================================================
__global__ __launch_bounds__(256) void pass3big_kernel(
    const unsigned short* __restrict__ y2bf,
    const float* __restrict__ g2, const float* __restrict__ bt2,
    const float* __restrict__ w3, const float* __restrict__ b3,
    float* __restrict__ stats, float* __restrict__ maxbuf, float* __restrict__ minbuf) {
    __shared__ float t2T[64 * LD];
    __shared__ float a2s[64], c2s[64];
    __shared__ float redM[4][128], redm[4][128], redS[4][128], redQ[4][128];
    const int tid = threadIdx.x, blk = blockIdx.x;
    fold64(stats + S2SUM, stats + S2SQ, g2, bt2, tid, a2s, c2s);
    __syncthreads();
    {
        const int cch = tid >> 2, r0 = (tid & 3) * 16;
        const float a2 = a2s[cch], c2 = c2s[cch];
        const uint4 u0 = *reinterpret_cast<const uint4*>(&y2bf[(size_t)blk * 4096 + cch * 64 + r0]);
        const uint4 u1 = *reinterpret_cast<const uint4*>(&y2bf[(size_t)blk * 4096 + cch * 64 + r0 + 8]);
        const unsigned short* us0 = reinterpret_cast<const unsigned short*>(&u0);
        const unsigned short* us1 = reinterpret_cast<const unsigned short*>(&u1);
#pragma unroll
        for (int j = 0; j < 8; ++j) {
            t2T[cch * LD + r0 + j]     = fmaxf(0.f, fmaf(a2, bf2f(us0[j]), c2));
            t2T[cch * LD + r0 + 8 + j] = fmaxf(0.f, fmaf(a2, bf2f(us1[j]), c2));
        }
    }
    __syncthreads();

    const int c0 = tid & 63, rg2 = tid >> 6;
    const int rb = rg2 * 16;
    float acc0[16], acc1[16];
    const float bv0 = b3[c0], bv1 = b3[c0 + 64];
#pragma unroll
    for (int j = 0; j < 16; ++j) { acc0[j] = bv0; acc1[j] = bv1; }
    for (int half = 0; half < 2; ++half) {
        float wr0[32], wr1[32];
#pragma unroll
        for (int k = 0; k < 32; ++k) {
            wr0[k] = w3[c0 * 64 + half * 32 + k];
            wr1[k] = w3[(c0 + 64) * 64 + half * 32 + k];
        }
#pragma unroll
        for (int k = 0; k < 32; ++k) {
            const int kk = half * 32 + k;
            float f[16];
            *reinterpret_cast<float4*>(&f[0])  = *reinterpret_cast<const float4*>(&t2T[kk * LD + rb]);
            *reinterpret_cast<float4*>(&f[4])  = *reinterpret_cast<const float4*>(&t2T[kk * LD + rb + 4]);
            *reinterpret_cast<float4*>(&f[8])  = *reinterpret_cast<const float4*>(&t2T[kk * LD + rb + 8]);
            *reinterpret_cast<float4*>(&f[12]) = *reinterpret_cast<const float4*>(&t2T[kk * LD + rb + 12]);
            const float w0 = wr0[k], w1v = wr1[k];
#pragma unroll
            for (int j = 0; j < 16; ++j) {
                acc0[j] = fmaf(f[j], w0, acc0[j]);
                acc1[j] = fmaf(f[j], w1v, acc1[j]);
            }
        }
    }
    float maxv0 = -3.4e38f, minv0 = 3.4e38f, ssum0 = 0.f, ssq0 = 0.f;
    float maxv1 = -3.4e38f, minv1 = 3.4e38f, ssum1 = 0.f, ssq1 = 0.f;
#pragma unroll
    for (int j = 0; j < 16; ++j) {
        maxv0 = fmaxf(maxv0, acc0[j]); minv0 = fminf(minv0, acc0[j]);
        ssum0 += acc0[j]; ssq0 = fmaf(acc0[j], acc0[j], ssq0);
        maxv1 = fmaxf(maxv1, acc1[j]); minv1 = fminf(minv1, acc1[j]);
        ssum1 += acc1[j]; ssq1 = fmaf(acc1[j], acc1[j], ssq1);
    }
    redM[rg2][c0] = maxv0; redM[rg2][c0 + 64] = maxv1;
    redm[rg2][c0] = minv0; redm[rg2][c0 + 64] = minv1;
    redS[rg2][c0] = ssum0; redS[rg2][c0 + 64] = ssum1;
    redQ[rg2][c0] = ssq0;  redQ[rg2][c0 + 64] = ssq1;
    __syncthreads();
    {
        const int g2i = tid >> 7, cc = tid & 127;
        const int g = blk * 2 + g2i;
        maxbuf[(size_t)g * 128 + cc] = fmaxf(redM[2 * g2i][cc], redM[2 * g2i + 1][cc]);
        minbuf[(size_t)g * 128 + cc] = fminf(redm[2 * g2i][cc], redm[2 * g2i + 1][cc]);
    }
    if (tid < 128) {
        const float s = (redS[0][tid] + redS[1][tid]) + (redS[2][tid] + redS[3][tid]);
        const float q = (redQ[0][tid] + redQ[1][tid]) + (redQ[2][tid] + redQ[3][tid]);
        const int slot = blk & (NSLOT - 1);
        atomicAdd(&stats[S3SUM + slot * 128 + tid], s);
        atomicAdd(&stats[S3SQ + slot * 128 + tid], q);
    }
}

// =====================================================================
// P3: full recompute variant (med/small ws). Stats3 + (MM) max/min.
// =====================================================================
template<bool MM>
__global__ __launch_bounds__(256) void pass3_kernel(
    const float* __restrict__ xyz, const float* __restrict__ points,
    const float* __restrict__ newxyz, const int* __restrict__ gidx,
    const float* __restrict__ w1, const float* __restrict__ b1,
    const float* __restrict__ g1, const float* __restrict__ bt1,
    const float* __restrict__ w2, const float* __restrict__ b2,
    const float* __restrict__ g2, const float* __restrict__ bt2,
    const float* __restrict__ w3, const float* __restrict__ b3,
    float* __restrict__ stats, float* __restrict__ maxbuf, float* __restrict__ minbuf) {
    __shared__ float bufA[67 * LD];
    __shared__ float t1T[64 * LD];
    __shared__ float a1s[64], c1s[64], a2s[64], c2s[64];
    __shared__ float redM[4][128], redm[4][128], redS[4][128], redQ[4][128];
    const int tid = threadIdx.x, blk = blockIdx.x;
    fold64(stats + S1SUM, stats + S1SQ, g1, bt1, tid, a1s, c1s);
    fold64(stats + S2SUM, stats + S2SQ, g2, bt2, tid, a2s, c2s);
    stage64(xyz, points, newxyz, gidx, blk * 64, tid, bufA);
    __syncthreads();
    mm_bnrelu<67>(w1, b1, bufA, t1T, a1s, c1s, tid);
    __syncthreads();
    mm_bnrelu<64>(w2, b2, t1T, bufA, a2s, c2s, tid);
    __syncthreads();

    const int c0 = tid & 63, rg2 = tid >> 6;
    const int rb = rg2 * 16;
    float acc0[16], acc1[16];
    const float bv0 = b3[c0], bv1 = b3[c0 + 64];
#pragma unroll
    for (int j = 0; j < 16; ++j) { acc0[j] = bv0; acc1[j] = bv1; }
    for (int half = 0; half < 2; ++half) {
        float wr0[32], wr1[32];
#pragma unroll
        for (int k = 0; k < 32; ++k) {
            wr0[k] = w3[c0 * 64 + half * 32 + k];
            wr1[k] = w3[(c0 + 64) * 64 + half * 32 + k];
        }
#pragma unroll
        for (int k = 0; k < 32; ++k) {
            const int kk = half * 32 + k;
            float f[16];
            *reinterpret_cast<float4*>(&f[0])  = *reinterpret_cast<const float4*>(&bufA[kk * LD + rb]);
            *reinterpret_cast<float4*>(&f[4])  = *reinterpret_cast<const float4*>(&bufA[kk * LD + rb + 4]);
            *reinterpret_cast<float4*>(&f[8])  = *reinterpret_cast<const float4*>(&bufA[kk * LD + rb + 8]);
            *reinterpret_cast<float4*>(&f[12]) = *reinterpret_cast<const float4*>(&bufA[kk * LD + rb + 12]);
            const float w0 = wr0[k], w1v = wr1[k];
#pragma unroll
            for (int j = 0; j < 16; ++j) {
                acc0[j] = fmaf(f[j], w0, acc0[j]);
                acc1[j] = fmaf(f[j], w1v, acc1[j]);
            }
        }
    }
    float maxv0 = -3.4e38f, minv0 = 3.4e38f, ssum0 = 0.f, ssq0 = 0.f;
    float maxv1 = -3.4e38f, minv1 = 3.4e38f, ssum1 = 0.f, ssq1 = 0.f;
#pragma unroll
    for (int j = 0; j < 16; ++j) {
        maxv0 = fmaxf(maxv0, acc0[j]); minv0 = fminf(minv0, acc0[j]);
        ssum0 += acc0[j]; ssq0 = fmaf(acc0[j], acc0[j], ssq0);
        maxv1 = fmaxf(maxv1, acc1[j]); minv1 = fminf(minv1, acc1[j]);
        ssum1 += acc1[j]; ssq1 = fmaf(acc1[j], acc1[j], ssq1);
    }
    redM[rg2][c0] = maxv0; redM[rg2][c0 + 64] = maxv1;
    redm[rg2][c0] = minv0; redm[rg2][c0 + 64] = minv1;
    redS[rg2][c0] = ssum0; redS[rg2][c0 + 64] = ssum1;
    redQ[rg2][c0] = ssq0;  redQ[rg2][c0 + 64] = ssq1;
    __syncthreads();
    if (MM) {
        const int g2i = tid >> 7, cc = tid & 127;
        const int g = blk * 2 + g2i;
        maxbuf[(size_t)g * 128 + cc] = fmaxf(redM[2 * g2i][cc], redM[2 * g2i + 1][cc]);
        minbuf[(size_t)g * 128 + cc] = fminf(redm[2 * g2i][cc], redm[2 * g2i + 1][cc]);
    }
    if (tid < 128) {
        const float s = (redS[0][tid] + redS[1][tid]) + (redS[2][tid] + redS[3][tid]);
        const float q = (redQ[0][tid] + redQ[1][tid]) + (redQ[2][tid] + redQ[3][tid]);
        const int slot = blk & (NSLOT - 1);
        atomicAdd(&stats[S3SUM + slot * 128 + tid], s);
        atomicAdd(&stats[S3SQ + slot * 128 + tid], q);
    }
}

// =====================================================================
// P4 (small-ws fallback): full recompute + BN3 + ReLU + maxpool -> out.
// =====================================================================
__global__ __launch_bounds__(256) void pass4_kernel(
    const float* __restrict__ xyz, const float* __restrict__ points,
    const float* __restrict__ newxyz, const int* __restrict__ gidx,
    const float* __restrict__ w1, const float* __restrict__ b1,
    const float* __restrict__ g1, const float* __restrict__ bt1,
    const float* __restrict__ w2, const float* __restrict__ b2,
    const float* __restrict__ g2, const float* __restrict__ bt2,
    const float* __restrict__ w3, const float* __restrict__ b3,
    const float* __restrict__ g3, const float* __restrict__ bt3,
    const float* __restrict__ stats, float* __restrict__ outp) {
    __shared__ float bufA[67 * LD];
    __shared__ float t1T[64 * LD];
    __shared__ float a1s[64], c1s[64], a2s[64], c2s[64];
    __shared__ float a3s[128], c3s[128];
    const int tid = threadIdx.x, blk = blockIdx.x;
    fold64(stats + S1SUM, stats + S1SQ, g1, bt1, tid, a1s, c1s);
    fold64(stats + S2SUM, stats + S2SQ, g2, bt2, tid, a2s, c2s);
    if (tid < 128) {
        float s = 0.f, q = 0.f;
#pragma unroll
        for (int sl = 0; sl < NSLOT; ++sl) { s += stats[S3SUM + sl * 128 + tid]; q += stats[S3SQ + sl * 128 + tid]; }
        const float Ninv = 1.0f / (float)NROWS;
        const float mean = s * Ninv;
        const float var  = fmaf(-mean, mean, q * Ninv);
        const float a    = g3[tid] * rsqrtf(var + BN_EPS);
        a3s[tid] = a;
        c3s[tid] = bt3[tid] - mean * a;
    }
    stage64(xyz, points, newxyz, gidx, blk * 64, tid, bufA);
    __syncthreads();
    mm_bnrelu<67>(w1, b1, bufA, t1T, a1s, c1s, tid);
    __syncthreads();
    mm_bnrelu<64>(w2, b2, t1T, bufA, a2s, c2s, tid);
    __syncthreads();

    const int c2 = tid & 127, rg2 = tid >> 7;
    float wr[64];
#pragma unroll
    for (int k = 0; k < 64; ++k) wr[k] = w3[c2 * 64 + k];
    const float bv = b3[c2];
    const float av = a3s[c2], cv = c3s[c2];
    float maxv = -3.4e38f;
#pragma unroll
    for (int bat = 0; bat < 4; ++bat) {
        const int rb = rg2 * 32 + bat * 8;
        float acc[8];
#pragma unroll
        for (int j = 0; j < 8; ++j) acc[j] = bv;
#pragma unroll
        for (int k = 0; k < 64; ++k) {
            float f[8];
            *reinterpret_cast<float4*>(&f[0]) = *reinterpret_cast<const float4*>(&bufA[k * LD + rb]);
            *reinterpret_cast<float4*>(&f[4]) = *reinterpret_cast<const float4*>(&bufA[k * LD + rb + 4]);
            const float wv = wr[k];
#pragma unroll
            for (int j = 0; j < 8; ++j) acc[j] = fmaf(f[j], wv, acc[j]);
        }
#pragma unroll
        for (int j = 0; j < 8; ++j) maxv = fmaxf(maxv, fmaxf(0.f, fmaf(av, acc[j], cv)));
    }
    const int g = blk * 2 + rg2;
    outp[(size_t)g * 128 + c2] = maxv;
}

// =====================================================================
// derive3 + final
// =====================================================================
__global__ void derive3_kernel(const float* __restrict__ g3, const float* __restrict__ bt3,
                               float* __restrict__ stats) {
    const int c = threadIdx.x;  // 128
    float s = 0.f, q = 0.f;
#pragma unroll
    for (int sl = 0; sl < NSLOT; ++sl) { s += stats[S3SUM + sl * 128 + c]; q += stats[S3SQ + sl * 128 + c]; }
    const float Ninv = 1.0f / (float)NROWS;
    const float mean = s * Ninv;
    const float var  = fmaf(-mean, mean, q * Ninv);
    const float a    = g3[c] * rsqrtf(var + BN_EPS);
    stats[A3OFF + c] = a;
    stats[C3OFF + c] = bt3[c] - mean * a;
}

__global__ __launch_bounds__(256) void final_kernel(
    const float* __restrict__ maxbuf, const float* __restrict__ minbuf,
    const float* __restrict__ stats, float* __restrict__ outp) {
    const int gid = blockIdx.x * 256 + threadIdx.x;
    if (gid >= NB * NPOINT * 128) return;
    const int c = gid & 127;
    const float a  = stats[A3OFF + c];
    const float cc = stats[C3OFF + c];
    const float v  = (a >= 0.f) ? maxbuf[gid] : minbuf[gid];
    outp[gid] = fmaxf(0.f, fmaf(a, v, cc));
}

// =====================================================================
extern "C" void kernel_launch(void* const* d_in, const int* in_sizes, int n_in,
                              void* d_out, int out_size, void* d_ws, size_t ws_size,
                              hipStream_t stream) {
    const float* xyz    = (const float*)d_in[0];
    const float* points = (const float*)d_in[1];
    const float* w1 = (const float*)d_in[2];
    const float* b1 = (const float*)d_in[3];
    const float* g1 = (const float*)d_in[4];
    const float* bt1 = (const float*)d_in[5];
    const float* w2 = (const float*)d_in[6];
    const float* b2 = (const float*)d_in[7];
    const float* g2 = (const float*)d_in[8];
    const float* bt2 = (const float*)d_in[9];
    const float* w3 = (const float*)d_in[10];
    const float* b3 = (const float*)d_in[11];
    const float* g3 = (const float*)d_in[12];
    const float* bt3 = (const float*)d_in[13];

    float* out_newxyz = (float*)d_out;
    float* out_newpts = (float*)d_out + NB * NPOINT * 3;

    char* ws = (char*)d_ws;
    if (ws_size < SMALL_TOTAL) return;  // cannot run at all

    int*   gidx   = (int*)(ws + OFF_GIDX);
    float* stats  = (float*)(ws + OFF_STATS);
    float* maxbuf = (float*)(ws + OFF_MAX);
    float* minbuf = (float*)(ws + OFF_MIN);
    unsigned short* y2bf = (unsigned short*)(ws + OFF_Y2BF);
    unsigned short* y1bf = (unsigned short*)(ws + OFF_Y1BF);
    const bool med  = (ws_size >= MED_TOTAL);
    const bool big  = (ws_size >= BIG_TOTAL);
    const bool big2 = (ws_size >= BIG2_TOTAL);

    hipMemsetAsync(stats, 0, 65536, stream);

    fps_kernel<<<NB, 512, 0, stream>>>(xyz, out_newxyz);
    query_kernel<<<(NB * NPOINT * 64) / 256, 256, 0, stream>>>(xyz, out_newxyz, gidx);
    if (big2) {
        pass1_kernel<true><<<NROWS / 64, 256, 0, stream>>>(xyz, points, out_newxyz, gidx,
                                                           w1, b1, stats, y1bf);
        pass2big_kernel<<<NROWS / 64, 256, 0, stream>>>(y1bf, g1, bt1, w2, b2, stats, y2bf);
        pass3big_kernel<<<NROWS / 64, 256, 0, stream>>>(y2bf, g2, bt2, w3, b3,
                                                        stats, maxbuf, minbuf);
        derive3_kernel<<<1, 128, 0, stream>>>(g3, bt3, stats);
        final_kernel<<<(NB * NPOINT * 128) / 256, 256, 0, stream>>>(maxbuf, minbuf, stats, out_newpts);
    } else if (big) {
        pass1_kernel<false><<<NROWS / 64, 256, 0, stream>>>(xyz, points, out_newxyz, gidx,
                                                            w1, b1, stats, y1bf);
        pass2_kernel<true><<<NROWS / 64, 256, 0, stream>>>(xyz, points, out_newxyz, gidx,
                                                           w1, b1, g1, bt1, w2, b2, stats, y2bf);
        pass3big_kernel<<<NROWS / 64, 256, 0, stream>>>(y2bf, g2, bt2, w3, b3,
                                                        stats, maxbuf, minbuf);
        derive3_kernel<<<1, 128, 0, stream>>>(g3, bt3, stats);
        final_kernel<<<(NB * NPOINT * 128) / 256, 256, 0, stream>>>(maxbuf, minbuf, stats, out_newpts);
    } else if (med) {
        pass1_kernel<false><<<NROWS / 64, 256, 0, stream>>>(xyz, points, out_newxyz, gidx,
                                                            w1, b1, stats, y1bf);
        pass2_kernel<false><<<NROWS / 64, 256, 0, stream>>>(xyz, points, out_newxyz, gidx,
                                                            w1, b1, g1, bt1, w2, b2, stats, y2bf);
        pass3_kernel<true><<<NROWS / 64, 256, 0, stream>>>(xyz, points, out_newxyz, gidx,
                                                           w1, b1, g1, bt1, w2, b2, g2, bt2,
                                                           w3, b3, stats, maxbuf, minbuf);
        derive3_kernel<<<1, 128, 0, stream>>>(g3, bt3, stats);
        final_kernel<<<(NB * NPOINT * 128) / 256, 256, 0, stream>>>(maxbuf, minbuf, stats, out_newpts);
    } else {
        pass1_kernel<false><<<NROWS / 64, 256, 0, stream>>>(xyz, points, out_newxyz, gidx,
                                                            w1, b1, stats, y1bf);
        pass2_kernel<false><<<NROWS / 64, 256, 0, stream>>>(xyz, points, out_newxyz, gidx,
                                                            w1, b1, g1, bt1, w2, b2, stats, y2bf);
        pass3_kernel<false><<<NROWS / 64, 256, 0, stream>>>(xyz, points, out_newxyz, gidx,
                                                            w1, b1, g1, bt1, w2, b2, g2, bt2,
                                                            w3, b3, stats, maxbuf, minbuf);
        pass4_kernel<<<NROWS / 64, 256, 0, stream>>>(xyz, points, out_newxyz, gidx,
                                                     w1, b1, g1, bt1, w2, b2, g2, bt2,
                                                     w3, b3, g3, bt3, stats, out_newpts);
    }
}

// Round 15
// 1054.181 us; speedup vs baseline: 1.3266x; 1.3266x over previous
//
#include <hip/hip_runtime.h>
#include <cstdint>

#define NB 16
#define NN 4096
#define ND 64
#define NPOINT 1024
#define NSAMPLE 32
#define NROWS (NB * NPOINT * NSAMPLE)   // 524288 rows through the MLP
#define BN_EPS 1e-5f
#define NSLOT 32
#define LD 68                            // LDS tile leading dim (rows+pad)

// ---------------- ws layout (bytes) ----------------
#define OFF_GIDX   0
#define OFF_STATS  (2 * 1024 * 1024)
#define OFF_MAX    (OFF_STATS + 131072)
#define OFF_MIN    (OFF_MAX + 8388608)
#define MED_TOTAL  ((size_t)OFF_MIN + 8388608)       // ~18.1 MB
#define SMALL_TOTAL ((size_t)OFF_MAX)                // ~2.1 MB
#define OFF_Y2BF   MED_TOTAL                         // bf16 y2: 64 MB
#define BIG_TOTAL  (OFF_Y2BF + (size_t)NROWS * 64 * 2)    // ~82.1 MB
#define OFF_Y1BF   BIG_TOTAL                         // bf16 y1: 64 MB
#define BIG2_TOTAL (OFF_Y1BF + (size_t)NROWS * 64 * 2)    // ~146.2 MB

// stats area float offsets
#define S1SUM 0
#define S1SQ  2048
#define S2SUM 4096
#define S2SQ  6144
#define S3SUM 8192
#define S3SQ  12288
#define A3OFF 16384
#define C3OFF 16512

__device__ __forceinline__ unsigned short f2bf(float f) {
    const unsigned u = __float_as_uint(f);
    return (unsigned short)((u + 0x7FFFu + ((u >> 16) & 1u)) >> 16);   // RNE
}
__device__ __forceinline__ float bf2f(unsigned short s) {
    return __uint_as_float(((unsigned)s) << 16);
}

// DPP-based wave64 fmax reduce step (ctrl/mask are template constants).
// bound_ctrl=true fills invalid lanes with 0 = fmax identity here (all >= 0).
template<int CTRL, int ROW_MASK>
__device__ __forceinline__ float dpp_fmax(float v) {
    const int mv = __builtin_amdgcn_update_dpp(0, __float_as_int(v), CTRL, ROW_MASK, 0xF, true);
    return fmaxf(v, __int_as_float(mv));
}

// =====================================================================
// K1: farthest point sampling. One block (256 thr = 4 waves) per batch.
// CONTIGUOUS 16 pts/lane (lane order == index order). Wave max via DPP
// (row_shr 1/2/4/8 + row_bcast 15/31 -> lane 63), index recovered via
// ballot+ctz+readlane. float4 parity slots; one barrier/iter. Exact np
// arithmetic; first-index tie-break by construction:
//  - within lane: ascending k, strict >
//  - within wave: lowest tied lane (= smallest index, contiguity)
//  - across waves: sequential slot scan, strict > (lowest wave wins)
// =====================================================================
__global__ __launch_bounds__(256) void fps_kernel(const float* __restrict__ xyz,
                                                  float* __restrict__ out_newxyz) {
    __shared__ float pxyz[NN * 3];      // 48 KB
    __shared__ float4 slot[2][4];       // {val, x, y, z} per wave, parity-buffered
    const int b = blockIdx.x, tid = threadIdx.x;
    const int wave = tid >> 6, lane = tid & 63;
    const float* base = xyz + (size_t)b * NN * 3;

    for (int i = tid; i < NN * 3 / 4; i += 256)
        reinterpret_cast<float4*>(pxyz)[i] = reinterpret_cast<const float4*>(base)[i];
    __syncthreads();

    // registers: lane tid holds points p = tid*16 + k (contiguous)
    float X[16], Y[16], Z[16], D[16];
#pragma unroll
    for (int k = 0; k < 16; ++k) {
        const int p = tid * 16 + k;
        X[k] = pxyz[3 * p + 0];
        Y[k] = pxyz[3 * p + 1];
        Z[k] = pxyz[3 * p + 2];
        D[k] = 1e10f;
    }

    float cx = pxyz[0], cy = pxyz[1], cz = pxyz[2];   // initial farthest = 0
    float* outb = out_newxyz + (size_t)b * NPOINT * 3;

    for (int it = 0; it < NPOINT; ++it) {
        if (tid == 0) {
            outb[it * 3 + 0] = cx;
            outb[it * 3 + 1] = cy;
            outb[it * 3 + 2] = cz;
        }
        float bv = -1.0f;
        int   bi = 0;
#pragma unroll
        for (int k = 0; k < 16; ++k) {
            const float dx = __fsub_rn(X[k], cx);
            const float dy = __fsub_rn(Y[k], cy);
            const float dz = __fsub_rn(Z[k], cz);
            const float d  = __fadd_rn(__fadd_rn(__fmul_rn(dx, dx), __fmul_rn(dy, dy)),
                                       __fmul_rn(dz, dz));
            const float nd = fminf(D[k], d);
            D[k] = nd;
            if (nd > bv) { bv = nd; bi = tid * 16 + k; }  // strict > keeps smallest idx in-lane
        }
        // wave64 max reduce via DPP (VALU only, no LDS)
        float v = bv;
        v = dpp_fmax<0x111, 0xF>(v);   // row_shr:1
        v = dpp_fmax<0x112, 0xF>(v);   // row_shr:2
        v = dpp_fmax<0x114, 0xF>(v);   // row_shr:4
        v = dpp_fmax<0x118, 0xF>(v);   // row_shr:8  -> lane15 of each row = row max
        v = dpp_fmax<0x142, 0xA>(v);   // row_bcast:15 into rows 1,3
        v = dpp_fmax<0x143, 0xC>(v);   // row_bcast:31 into rows 2,3 -> lane63 = wave max
        const float wmax = __int_as_float(__builtin_amdgcn_readlane(__float_as_int(v), 63));
        const unsigned long long mask = __ballot(bv == wmax);
        const int src  = (int)__builtin_ctzll(mask);     // lowest tied lane
        const int widx = __builtin_amdgcn_readlane(bi, src);
        const int par = it & 1;
        if (lane == 0) {
            slot[par][wave] = make_float4(wmax, pxyz[3 * widx + 0],
                                                pxyz[3 * widx + 1],
                                                pxyz[3 * widx + 2]);
        }
        __syncthreads();
        float4 best = slot[par][0];
#pragma unroll
        for (int w = 1; w < 4; ++w) {
            const float4 s = slot[par][w];
            if (s.x > best.x) best = s;   // strict > : lowest wave wins ties
        }
        cx = best.y; cy = best.z; cz = best.w;
    }
}

// =====================================================================
// K2: query_ball_point. One wave per query; ordered prefix selection of
// first NSAMPLE idx with d^2 <= r^2. 2 chunks (128 pts) per loop iter.
// =====================================================================
__global__ __launch_bounds__(256) void query_kernel(const float* __restrict__ xyz,
                                                    const float* __restrict__ newxyz,
                                                    int* __restrict__ gidx) {
    const int gtid = blockIdx.x * 256 + threadIdx.x;
    const int q    = gtid >> 6;
    const int lane = threadIdx.x & 63;
    if (q >= NB * NPOINT) return;
    const int b = q >> 10;
    const float* xb = xyz + (size_t)b * NN * 3;
    const float cx = newxyz[q * 3 + 0];
    const float cy = newxyz[q * 3 + 1];
    const float cz = newxyz[q * 3 + 2];
    const float snew = __fadd_rn(__fadd_rn(__fmul_rn(cx, cx), __fmul_rn(cy, cy)),
                                 __fmul_rn(cz, cz));
    const float rsq = (float)(0.2 * 0.2);
    int* outq = gidx + (size_t)q * NSAMPLE;

    int count = 0, first = 0;
    for (int base = 0; base < NN; base += 128) {
        const int pA = base + lane, pB = base + 64 + lane;
        const float xA = xb[pA * 3 + 0], yA = xb[pA * 3 + 1], zA = xb[pA * 3 + 2];
        const float xB = xb[pB * 3 + 0], yB = xb[pB * 3 + 1], zB = xb[pB * 3 + 2];
        const float sxA = __fadd_rn(__fadd_rn(__fmul_rn(xA, xA), __fmul_rn(yA, yA)),
                                    __fmul_rn(zA, zA));
        const float sxB = __fadd_rn(__fadd_rn(__fmul_rn(xB, xB), __fmul_rn(yB, yB)),
                                    __fmul_rn(zB, zB));
        float dotA = __fmul_rn(cx, xA);
        dotA = fmaf(cy, yA, dotA);
        dotA = fmaf(cz, zA, dotA);
        float dotB = __fmul_rn(cx, xB);
        dotB = fmaf(cy, yB, dotB);
        dotB = fmaf(cz, zB, dotB);
        const float sqA = __fadd_rn(__fsub_rn(snew, __fadd_rn(dotA, dotA)), sxA);
        const float sqB = __fadd_rn(__fsub_rn(snew, __fadd_rn(dotB, dotB)), sxB);
        const bool qualA = !(sqA > rsq);
        const bool qualB = !(sqB > rsq);
        const unsigned long long maskA = __ballot(qualA);
        const unsigned long long maskB = __ballot(qualB);
        if (count == 0) {
            if (maskA)      first = base + (int)__builtin_ctzll(maskA);
            else if (maskB) first = base + 64 + (int)__builtin_ctzll(maskB);
        }
        const unsigned long long below = (1ull << lane) - 1ull;
        const int cA = __popcll(maskA);
        if (qualA) {
            const int pos = count + __popcll(maskA & below);
            if (pos < NSAMPLE) outq[pos] = pA;
        }
        if (qualB) {
            const int pos = count + cA + __popcll(maskB & below);
            if (pos < NSAMPLE) outq[pos] = pB;
        }
        count += cA + __popcll(maskB);
        if (count >= NSAMPLE) break;
    }
    if (count < NSAMPLE) {
        for (int pos = count + lane; pos < NSAMPLE; pos += 64) outq[pos] = first;
    }
}

// =====================================================================
// Shared device helpers for the 64-row tiled MLP passes.
// =====================================================================
__device__ __forceinline__ void stage64(const float* __restrict__ xyz,
                                        const float* __restrict__ points,
                                        const float* __restrict__ newxyz,
                                        const int* __restrict__ gidx,
                                        int row0, int tid, float* featT) {
    const int rl = tid >> 2, qd = tid & 3;
    const int R   = row0 + rl;
    const int grp = R >> 5;
    const int idx = gidx[R];
    const int b   = grp >> 10;
    const float* prow = points + ((size_t)b * NN + idx) * ND + qd * 16;
#pragma unroll
    for (int j = 0; j < 4; ++j) {
        const float4 v = *reinterpret_cast<const float4*>(prow + j * 4);
        const int k = 3 + qd * 16 + j * 4;
        featT[(k + 0) * LD + rl] = v.x;
        featT[(k + 1) * LD + rl] = v.y;
        featT[(k + 2) * LD + rl] = v.z;
        featT[(k + 3) * LD + rl] = v.w;
    }
    if (qd == 0) {
        const float* xr = xyz + ((size_t)b * NN + idx) * 3;
        const float* cr = newxyz + (size_t)grp * 3;
        featT[0 * LD + rl] = xr[0] - cr[0];
        featT[1 * LD + rl] = xr[1] - cr[1];
        featT[2 * LD + rl] = xr[2] - cr[2];
    }
}

__device__ __forceinline__ void fold64(const float* __restrict__ ssum,
                                       const float* __restrict__ ssq,
                                       const float* __restrict__ g,
                                       const float* __restrict__ bt,
                                       int tid, float* a_s, float* c_s) {
    if (tid < 64) {
        float s = 0.f, q = 0.f;
#pragma unroll
        for (int sl = 0; sl < NSLOT; ++sl) { s += ssum[sl * 64 + tid]; q += ssq[sl * 64 + tid]; }
        const float Ninv = 1.0f / (float)NROWS;
        const float mean = s * Ninv;
        const float var  = fmaf(-mean, mean, q * Ninv);
        const float a    = g[tid] * rsqrtf(var + BN_EPS);
        a_s[tid] = a;
        c_s[tid] = bt[tid] - mean * a;
    }
}

// y = inT @ w^T + b; out = relu(a*y + c), written transposed [64ch][LD]
template<int CIN>
__device__ __forceinline__ void mm_bnrelu(const float* __restrict__ w,
                                          const float* __restrict__ bias,
                                          const float* inT, float* outT,
                                          const float* a_s, const float* c_s, int tid) {
    const int c = tid & 63, rg = tid >> 6;
    float wr[CIN];
#pragma unroll
    for (int k = 0; k < CIN; ++k) wr[k] = w[c * CIN + k];
    const float bv = bias[c];
    const float av = a_s[c], cv = c_s[c];
#pragma unroll
    for (int bat = 0; bat < 2; ++bat) {
        const int rb = rg * 16 + bat * 8;
        float acc[8];
#pragma unroll
        for (int j = 0; j < 8; ++j) acc[j] = bv;
#pragma unroll
        for (int k = 0; k < CIN; ++k) {
            float f[8];
            *reinterpret_cast<float4*>(&f[0]) = *reinterpret_cast<const float4*>(&inT[k * LD + rb]);
            *reinterpret_cast<float4*>(&f[4]) = *reinterpret_cast<const float4*>(&inT[k * LD + rb + 4]);
            const float wv = wr[k];
#pragma unroll
            for (int j = 0; j < 8; ++j) acc[j] = fmaf(f[j], wv, acc[j]);
        }
        float o[8];
#pragma unroll
        for (int j = 0; j < 8; ++j) o[j] = fmaxf(0.f, fmaf(av, acc[j], cv));
        *reinterpret_cast<float4*>(&outT[c * LD + rb])     = *reinterpret_cast<float4*>(&o[0]);
        *reinterpret_cast<float4*>(&outT[c * LD + rb + 4]) = *reinterpret_cast<float4*>(&o[4]);
    }
}

// =====================================================================
// P1: stats for layer1 (Σy1, Σy1²). If ST, store raw y1 (pre-BN) bf16.
// =====================================================================
template<bool ST>
__global__ __launch_bounds__(256) void pass1_kernel(
    const float* __restrict__ xyz, const float* __restrict__ points,
    const float* __restrict__ newxyz, const int* __restrict__ gidx,
    const float* __restrict__ w1, const float* __restrict__ b1,
    float* __restrict__ stats, unsigned short* __restrict__ y1bf) {
    __shared__ float featT[67 * LD];
    __shared__ float red[4][64], redq[4][64];
    const int tid = threadIdx.x, blk = blockIdx.x;
    stage64(xyz, points, newxyz, gidx, blk * 64, tid, featT);
    __syncthreads();
    const int c = tid & 63, rg = tid >> 6;
    float wr[67];
#pragma unroll
    for (int k = 0; k < 67; ++k) wr[k] = w1[c * 67 + k];
    const float bv = b1[c];
    float ssum = 0.f, ssq = 0.f;
#pragma unroll
    for (int bat = 0; bat < 2; ++bat) {
        const int rb = rg * 16 + bat * 8;
        float acc[8];
#pragma unroll
        for (int j = 0; j < 8; ++j) acc[j] = bv;
#pragma unroll
        for (int k = 0; k < 67; ++k) {
            float f[8];
            *reinterpret_cast<float4*>(&f[0]) = *reinterpret_cast<const float4*>(&featT[k * LD + rb]);
            *reinterpret_cast<float4*>(&f[4]) = *reinterpret_cast<const float4*>(&featT[k * LD + rb + 4]);
            const float wv = wr[k];
#pragma unroll
            for (int j = 0; j < 8; ++j) acc[j] = fmaf(f[j], wv, acc[j]);
        }
        if (ST) {
            unsigned short o[8];
#pragma unroll
            for (int j = 0; j < 8; ++j) o[j] = f2bf(acc[j]);
            *reinterpret_cast<uint4*>(&y1bf[(size_t)blk * 4096 + c * 64 + rb]) =
                *reinterpret_cast<uint4*>(o);
        }
#pragma unroll
        for (int j = 0; j < 8; ++j) { ssum += acc[j]; ssq = fmaf(acc[j], acc[j], ssq); }
    }
    red[rg][c] = ssum;
    redq[rg][c] = ssq;
    __syncthreads();
    if (tid < 64) {
        const float s = red[0][tid] + red[1][tid] + red[2][tid] + red[3][tid];
        const float q = redq[0][tid] + redq[1][tid] + redq[2][tid] + redq[3][tid];
        const int slot = blk & (NSLOT - 1);
        atomicAdd(&stats[S1SUM + slot * 64 + tid], s);
        atomicAdd(&stats[S1SQ + slot * 64 + tid], q);
    }
}

// =====================================================================
// P2big: load bf16 y1 tile, t1 = relu(bn1(y1)), y2 matmul, store y2 bf16
// + stats2. No gather, no layer-1 recompute.
// =====================================================================
__global__ __launch_bounds__(256) void pass2big_kernel(
    const unsigned short* __restrict__ y1bf,
    const float* __restrict__ g1, const float* __restrict__ bt1,
    const float* __restrict__ w2, const float* __restrict__ b2,
    float* __restrict__ stats, unsigned short* __restrict__ y2bf) {
    __shared__ float t1T[64 * LD];
    __shared__ float a1s[64], c1s[64];
    __shared__ float red[4][64], redq[4][64];
    const int tid = threadIdx.x, blk = blockIdx.x;
    fold64(stats + S1SUM, stats + S1SQ, g1, bt1, tid, a1s, c1s);
    __syncthreads();
    {
        const int cch = tid >> 2, r0 = (tid & 3) * 16;
        const float a1 = a1s[cch], c1 = c1s[cch];
        const uint4 u0 = *reinterpret_cast<const uint4*>(&y1bf[(size_t)blk * 4096 + cch * 64 + r0]);
        const uint4 u1 = *reinterpret_cast<const uint4*>(&y1bf[(size_t)blk * 4096 + cch * 64 + r0 + 8]);
        const unsigned short* us0 = reinterpret_cast<const unsigned short*>(&u0);
        const unsigned short* us1 = reinterpret_cast<const unsigned short*>(&u1);
#pragma unroll
        for (int j = 0; j < 8; ++j) {
            t1T[cch * LD + r0 + j]     = fmaxf(0.f, fmaf(a1, bf2f(us0[j]), c1));
            t1T[cch * LD + r0 + 8 + j] = fmaxf(0.f, fmaf(a1, bf2f(us1[j]), c1));
        }
    }
    __syncthreads();
    const int c = tid & 63, rg = tid >> 6;
    float wr[64];
#pragma unroll
    for (int k = 0; k < 64; ++k) wr[k] = w2[c * 64 + k];
    const float bv = b2[c];
    float ssum = 0.f, ssq = 0.f;
#pragma unroll
    for (int bat = 0; bat < 2; ++bat) {
        const int rb = rg * 16 + bat * 8;
        float acc[8];
#pragma unroll
        for (int j = 0; j < 8; ++j) acc[j] = bv;
#pragma unroll
        for (int k = 0; k < 64; ++k) {
            float f[8];
            *reinterpret_cast<float4*>(&f[0]) = *reinterpret_cast<const float4*>(&t1T[k * LD + rb]);
            *reinterpret_cast<float4*>(&f[4]) = *reinterpret_cast<const float4*>(&t1T[k * LD + rb + 4]);
            const float wv = wr[k];
#pragma unroll
            for (int j = 0; j < 8; ++j) acc[j] = fmaf(f[j], wv, acc[j]);
        }
        {
            unsigned short o[8];
#pragma unroll
            for (int j = 0; j < 8; ++j) o[j] = f2bf(acc[j]);
            *reinterpret_cast<uint4*>(&y2bf[(size_t)blk * 4096 + c * 64 + rb]) =
                *reinterpret_cast<uint4*>(o);
        }
#pragma unroll
        for (int j = 0; j < 8; ++j) { ssum += acc[j]; ssq = fmaf(acc[j], acc[j], ssq); }
    }
    red[rg][c] = ssum;
    redq[rg][c] = ssq;
    __syncthreads();
    if (tid < 64) {
        const float s = red[0][tid] + red[1][tid] + red[2][tid] + red[3][tid];
        const float q = redq[0][tid] + redq[1][tid] + redq[2][tid] + redq[3][tid];
        const int slot = blk & (NSLOT - 1);
        atomicAdd(&stats[S2SUM + slot * 64 + tid], s);
        atomicAdd(&stats[S2SQ + slot * 64 + tid], q);
    }
}

// =====================================================================
// P2: full recompute variant. If ST stores y2 bf16.
// =====================================================================
template<bool ST>
__global__ __launch_bounds__(256) void pass2_kernel(
    const float* __restrict__ xyz, const float* __restrict__ points,
    const float* __restrict__ newxyz, const int* __restrict__ gidx,
    const float* __restrict__ w1, const float* __restrict__ b1,
    const float* __restrict__ g1, const float* __restrict__ bt1,
    const float* __restrict__ w2, const float* __restrict__ b2,
    float* __restrict__ stats, unsigned short* __restrict__ y2bf) {
    __shared__ float featT[67 * LD];
    __shared__ float t1T[64 * LD];
    __shared__ float a1s[64], c1s[64];
    __shared__ float red[4][64], redq[4][64];
    const int tid = threadIdx.x, blk = blockIdx.x;
    fold64(stats + S1SUM, stats + S1SQ, g1, bt1, tid, a1s, c1s);
    stage64(xyz, points, newxyz, gidx, blk * 64, tid, featT);
    __syncthreads();
    mm_bnrelu<67>(w1, b1, featT, t1T, a1s, c1s, tid);
    __syncthreads();
    const int c = tid & 63, rg = tid >> 6;
    float wr[64];
#pragma unroll
    for (int k = 0; k < 64; ++k) wr[k] = w2[c * 64 + k];
    const float bv = b2[c];
    float ssum = 0.f, ssq = 0.f;
#pragma unroll
    for (int bat = 0; bat < 2; ++bat) {
        const int rb = rg * 16 + bat * 8;
        float acc[8];
#pragma unroll
        for (int j = 0; j < 8; ++j) acc[j] = bv;
#pragma unroll
        for (int k = 0; k < 64; ++k) {
            float f[8];
            *reinterpret_cast<float4*>(&f[0]) = *reinterpret_cast<const float4*>(&t1T[k * LD + rb]);
            *reinterpret_cast<float4*>(&f[4]) = *reinterpret_cast<const float4*>(&t1T[k * LD + rb + 4]);
            const float wv = wr[k];
#pragma unroll
            for (int j = 0; j < 8; ++j) acc[j] = fmaf(f[j], wv, acc[j]);
        }
        if (ST) {
            unsigned short o[8];
#pragma unroll
            for (int j = 0; j < 8; ++j) o[j] = f2bf(acc[j]);
            *reinterpret_cast<uint4*>(&y2bf[(size_t)blk * 4096 + c * 64 + rb]) =
                *reinterpret_cast<uint4*>(o);
        }
#pragma unroll
        for (int j = 0; j < 8; ++j) { ssum += acc[j]; ssq = fmaf(acc[j], acc[j], ssq); }
    }
    red[rg][c] = ssum;
    redq[rg][c] = ssq;
    __syncthreads();
    if (tid < 64) {
        const float s = red[0][tid] + red[1][tid] + red[2][tid] + red[3][tid];
        const float q = redq[0][tid] + redq[1][tid] + redq[2][tid] + redq[3][tid];
        const int slot = blk & (NSLOT - 1);
        atomicAdd(&stats[S2SUM + slot * 64 + tid], s);
        atomicAdd(&stats[S2SQ + slot * 64 + tid], q);
    }
}

// =====================================================================
// P3big: load bf16 y2 tile, t2 = relu(bn2(y2)), y3 matmul (2-ch blocked),
// stats3 + per-(b,s,c) max/min.
// =====================================================================
__global__ __launch_bounds__(256) void pass3big_kernel(
    const unsigned short* __restrict__ y2bf,
    const float* __restrict__ g2, const float* __restrict__ bt2,
    const float* __restrict__ w3, const float* __restrict__ b3,
    float* __restrict__ stats, float* __restrict__ maxbuf, float* __restrict__ minbuf) {
    __shared__ float t2T[64 * LD];
    __shared__ float a2s[64], c2s[64];
    __shared__ float redM[4][128], redm[4][128], redS[4][128], redQ[4][128];
    const int tid = threadIdx.x, blk = blockIdx.x;
    fold64(stats + S2SUM, stats + S2SQ, g2, bt2, tid, a2s, c2s);
    __syncthreads();
    {
        const int cch = tid >> 2, r0 = (tid & 3) * 16;
        const float a2 = a2s[cch], c2 = c2s[cch];
        const uint4 u0 = *reinterpret_cast<const uint4*>(&y2bf[(size_t)blk * 4096 + cch * 64 + r0]);
        const uint4 u1 = *reinterpret_cast<const uint4*>(&y2bf[(size_t)blk * 4096 + cch * 64 + r0 + 8]);
        const unsigned short* us0 = reinterpret_cast<const unsigned short*>(&u0);
        const unsigned short* us1 = reinterpret_cast<const unsigned short*>(&u1);
#pragma unroll
        for (int j = 0; j < 8; ++j) {
            t2T[cch * LD + r0 + j]     = fmaxf(0.f, fmaf(a2, bf2f(us0[j]), c2));
            t2T[cch * LD + r0 + 8 + j] = fmaxf(0.f, fmaf(a2, bf2f(us1[j]), c2));
        }
    }
    __syncthreads();

    const int c0 = tid & 63, rg2 = tid >> 6;
    const int rb = rg2 * 16;
    float acc0[16], acc1[16];
    const float bv0 = b3[c0], bv1 = b3[c0 + 64];
#pragma unroll
    for (int j = 0; j < 16; ++j) { acc0[j] = bv0; acc1[j] = bv1; }
    for (int half = 0; half < 2; ++half) {
        float wr0[32], wr1[32];
#pragma unroll
        for (int k = 0; k < 32; ++k) {
            wr0[k] = w3[c0 * 64 + half * 32 + k];
            wr1[k] = w3[(c0 + 64) * 64 + half * 32 + k];
        }
#pragma unroll
        for (int k = 0; k < 32; ++k) {
            const int kk = half * 32 + k;
            float f[16];
            *reinterpret_cast<float4*>(&f[0])  = *reinterpret_cast<const float4*>(&t2T[kk * LD + rb]);
            *reinterpret_cast<float4*>(&f[4])  = *reinterpret_cast<const float4*>(&t2T[kk * LD + rb + 4]);
            *reinterpret_cast<float4*>(&f[8])  = *reinterpret_cast<const float4*>(&t2T[kk * LD + rb + 8]);
            *reinterpret_cast<float4*>(&f[12]) = *reinterpret_cast<const float4*>(&t2T[kk * LD + rb + 12]);
            const float w0 = wr0[k], w1v = wr1[k];
#pragma unroll
            for (int j = 0; j < 16; ++j) {
                acc0[j] = fmaf(f[j], w0, acc0[j]);
                acc1[j] = fmaf(f[j], w1v, acc1[j]);
            }
        }
    }
    float maxv0 = -3.4e38f, minv0 = 3.4e38f, ssum0 = 0.f, ssq0 = 0.f;
    float maxv1 = -3.4e38f, minv1 = 3.4e38f, ssum1 = 0.f, ssq1 = 0.f;
#pragma unroll
    for (int j = 0; j < 16; ++j) {
        maxv0 = fmaxf(maxv0, acc0[j]); minv0 = fminf(minv0, acc0[j]);
        ssum0 += acc0[j]; ssq0 = fmaf(acc0[j], acc0[j], ssq0);
        maxv1 = fmaxf(maxv1, acc1[j]); minv1 = fminf(minv1, acc1[j]);
        ssum1 += acc1[j]; ssq1 = fmaf(acc1[j], acc1[j], ssq1);
    }
    redM[rg2][c0] = maxv0; redM[rg2][c0 + 64] = maxv1;
    redm[rg2][c0] = minv0; redm[rg2][c0 + 64] = minv1;
    redS[rg2][c0] = ssum0; redS[rg2][c0 + 64] = ssum1;
    redQ[rg2][c0] = ssq0;  redQ[rg2][c0 + 64] = ssq1;
    __syncthreads();
    {
        const int g2i = tid >> 7, cc = tid & 127;
        const int g = blk * 2 + g2i;
        maxbuf[(size_t)g * 128 + cc] = fmaxf(redM[2 * g2i][cc], redM[2 * g2i + 1][cc]);
        minbuf[(size_t)g * 128 + cc] = fminf(redm[2 * g2i][cc], redm[2 * g2i + 1][cc]);
    }
    if (tid < 128) {
        const float s = (redS[0][tid] + redS[1][tid]) + (redS[2][tid] + redS[3][tid]);
        const float q = (redQ[0][tid] + redQ[1][tid]) + (redQ[2][tid] + redQ[3][tid]);
        const int slot = blk & (NSLOT - 1);
        atomicAdd(&stats[S3SUM + slot * 128 + tid], s);
        atomicAdd(&stats[S3SQ + slot * 128 + tid], q);
    }
}

// =====================================================================
// P3: full recompute variant (med/small ws). Stats3 + (MM) max/min.
// =====================================================================
template<bool MM>
__global__ __launch_bounds__(256) void pass3_kernel(
    const float* __restrict__ xyz, const float* __restrict__ points,
    const float* __restrict__ newxyz, const int* __restrict__ gidx,
    const float* __restrict__ w1, const float* __restrict__ b1,
    const float* __restrict__ g1, const float* __restrict__ bt1,
    const float* __restrict__ w2, const float* __restrict__ b2,
    const float* __restrict__ g2, const float* __restrict__ bt2,
    const float* __restrict__ w3, const float* __restrict__ b3,
    float* __restrict__ stats, float* __restrict__ maxbuf, float* __restrict__ minbuf) {
    __shared__ float bufA[67 * LD];
    __shared__ float t1T[64 * LD];
    __shared__ float a1s[64], c1s[64], a2s[64], c2s[64];
    __shared__ float redM[4][128], redm[4][128], redS[4][128], redQ[4][128];
    const int tid = threadIdx.x, blk = blockIdx.x;
    fold64(stats + S1SUM, stats + S1SQ, g1, bt1, tid, a1s, c1s);
    fold64(stats + S2SUM, stats + S2SQ, g2, bt2, tid, a2s, c2s);
    stage64(xyz, points, newxyz, gidx, blk * 64, tid, bufA);
    __syncthreads();
    mm_bnrelu<67>(w1, b1, bufA, t1T, a1s, c1s, tid);
    __syncthreads();
    mm_bnrelu<64>(w2, b2, t1T, bufA, a2s, c2s, tid);
    __syncthreads();

    const int c0 = tid & 63, rg2 = tid >> 6;
    const int rb = rg2 * 16;
    float acc0[16], acc1[16];
    const float bv0 = b3[c0], bv1 = b3[c0 + 64];
#pragma unroll
    for (int j = 0; j < 16; ++j) { acc0[j] = bv0; acc1[j] = bv1; }
    for (int half = 0; half < 2; ++half) {
        float wr0[32], wr1[32];
#pragma unroll
        for (int k = 0; k < 32; ++k) {
            wr0[k] = w3[c0 * 64 + half * 32 + k];
            wr1[k] = w3[(c0 + 64) * 64 + half * 32 + k];
        }
#pragma unroll
        for (int k = 0; k < 32; ++k) {
            const int kk = half * 32 + k;
            float f[16];
            *reinterpret_cast<float4*>(&f[0])  = *reinterpret_cast<const float4*>(&bufA[kk * LD + rb]);
            *reinterpret_cast<float4*>(&f[4])  = *reinterpret_cast<const float4*>(&bufA[kk * LD + rb + 4]);
            *reinterpret_cast<float4*>(&f[8])  = *reinterpret_cast<const float4*>(&bufA[kk * LD + rb + 8]);
            *reinterpret_cast<float4*>(&f[12]) = *reinterpret_cast<const float4*>(&bufA[kk * LD + rb + 12]);
            const float w0 = wr0[k], w1v = wr1[k];
#pragma unroll
            for (int j = 0; j < 16; ++j) {
                acc0[j] = fmaf(f[j], w0, acc0[j]);
                acc1[j] = fmaf(f[j], w1v, acc1[j]);
            }
        }
    }
    float maxv0 = -3.4e38f, minv0 = 3.4e38f, ssum0 = 0.f, ssq0 = 0.f;
    float maxv1 = -3.4e38f, minv1 = 3.4e38f, ssum1 = 0.f, ssq1 = 0.f;
#pragma unroll
    for (int j = 0; j < 16; ++j) {
        maxv0 = fmaxf(maxv0, acc0[j]); minv0 = fminf(minv0, acc0[j]);
        ssum0 += acc0[j]; ssq0 = fmaf(acc0[j], acc0[j], ssq0);
        maxv1 = fmaxf(maxv1, acc1[j]); minv1 = fminf(minv1, acc1[j]);
        ssum1 += acc1[j]; ssq1 = fmaf(acc1[j], acc1[j], ssq1);
    }
    redM[rg2][c0] = maxv0; redM[rg2][c0 + 64] = maxv1;
    redm[rg2][c0] = minv0; redm[rg2][c0 + 64] = minv1;
    redS[rg2][c0] = ssum0; redS[rg2][c0 + 64] = ssum1;
    redQ[rg2][c0] = ssq0;  redQ[rg2][c0 + 64] = ssq1;
    __syncthreads();
    if (MM) {
        const int g2i = tid >> 7, cc = tid & 127;
        const int g = blk * 2 + g2i;
        maxbuf[(size_t)g * 128 + cc] = fmaxf(redM[2 * g2i][cc], redM[2 * g2i + 1][cc]);
        minbuf[(size_t)g * 128 + cc] = fminf(redm[2 * g2i][cc], redm[2 * g2i + 1][cc]);
    }
    if (tid < 128) {
        const float s = (redS[0][tid] + redS[1][tid]) + (redS[2][tid] + redS[3][tid]);
        const float q = (redQ[0][tid] + redQ[1][tid]) + (redQ[2][tid] + redQ[3][tid]);
        const int slot = blk & (NSLOT - 1);
        atomicAdd(&stats[S3SUM + slot * 128 + tid], s);
        atomicAdd(&stats[S3SQ + slot * 128 + tid], q);
    }
}

// =====================================================================
// P4 (small-ws fallback): full recompute + BN3 + ReLU + maxpool -> out.
// =====================================================================
__global__ __launch_bounds__(256) void pass4_kernel(
    const float* __restrict__ xyz, const float* __restrict__ points,
    const float* __restrict__ newxyz, const int* __restrict__ gidx,
    const float* __restrict__ w1, const float* __restrict__ b1,
    const float* __restrict__ g1, const float* __restrict__ bt1,
    const float* __restrict__ w2, const float* __restrict__ b2,
    const float* __restrict__ g2, const float* __restrict__ bt2,
    const float* __restrict__ w3, const float* __restrict__ b3,
    const float* __restrict__ g3, const float* __restrict__ bt3,
    const float* __restrict__ stats, float* __restrict__ outp) {
    __shared__ float bufA[67 * LD];
    __shared__ float t1T[64 * LD];
    __shared__ float a1s[64], c1s[64], a2s[64], c2s[64];
    __shared__ float a3s[128], c3s[128];
    const int tid = threadIdx.x, blk = blockIdx.x;
    fold64(stats + S1SUM, stats + S1SQ, g1, bt1, tid, a1s, c1s);
    fold64(stats + S2SUM, stats + S2SQ, g2, bt2, tid, a2s, c2s);
    if (tid < 128) {
        float s = 0.f, q = 0.f;
#pragma unroll
        for (int sl = 0; sl < NSLOT; ++sl) { s += stats[S3SUM + sl * 128 + tid]; q += stats[S3SQ + sl * 128 + tid]; }
        const float Ninv = 1.0f / (float)NROWS;
        const float mean = s * Ninv;
        const float var  = fmaf(-mean, mean, q * Ninv);
        const float a    = g3[tid] * rsqrtf(var + BN_EPS);
        a3s[tid] = a;
        c3s[tid] = bt3[tid] - mean * a;
    }
    stage64(xyz, points, newxyz, gidx, blk * 64, tid, bufA);
    __syncthreads();
    mm_bnrelu<67>(w1, b1, bufA, t1T, a1s, c1s, tid);
    __syncthreads();
    mm_bnrelu<64>(w2, b2, t1T, bufA, a2s, c2s, tid);
    __syncthreads();

    const int c2 = tid & 127, rg2 = tid >> 7;
    float wr[64];
#pragma unroll
    for (int k = 0; k < 64; ++k) wr[k] = w3[c2 * 64 + k];
    const float bv = b3[c2];
    const float av = a3s[c2], cv = c3s[c2];
    float maxv = -3.4e38f;
#pragma unroll
    for (int bat = 0; bat < 4; ++bat) {
        const int rb = rg2 * 32 + bat * 8;
        float acc[8];
#pragma unroll
        for (int j = 0; j < 8; ++j) acc[j] = bv;
#pragma unroll
        for (int k = 0; k < 64; ++k) {
            float f[8];
            *reinterpret_cast<float4*>(&f[0]) = *reinterpret_cast<const float4*>(&bufA[k * LD + rb]);
            *reinterpret_cast<float4*>(&f[4]) = *reinterpret_cast<const float4*>(&bufA[k * LD + rb + 4]);
            const float wv = wr[k];
#pragma unroll
            for (int j = 0; j < 8; ++j) acc[j] = fmaf(f[j], wv, acc[j]);
        }
#pragma unroll
        for (int j = 0; j < 8; ++j) maxv = fmaxf(maxv, fmaxf(0.f, fmaf(av, acc[j], cv)));
    }
    const int g = blk * 2 + rg2;
    outp[(size_t)g * 128 + c2] = maxv;
}

// =====================================================================
// derive3 + final
// =====================================================================
__global__ void derive3_kernel(const float* __restrict__ g3, const float* __restrict__ bt3,
                               float* __restrict__ stats) {
    const int c = threadIdx.x;  // 128
    float s = 0.f, q = 0.f;
#pragma unroll
    for (int sl = 0; sl < NSLOT; ++sl) { s += stats[S3SUM + sl * 128 + c]; q += stats[S3SQ + sl * 128 + c]; }
    const float Ninv = 1.0f / (float)NROWS;
    const float mean = s * Ninv;
    const float var  = fmaf(-mean, mean, q * Ninv);
    const float a    = g3[c] * rsqrtf(var + BN_EPS);
    stats[A3OFF + c] = a;
    stats[C3OFF + c] = bt3[c] - mean * a;
}

__global__ __launch_bounds__(256) void final_kernel(
    const float* __restrict__ maxbuf, const float* __restrict__ minbuf,
    const float* __restrict__ stats, float* __restrict__ outp) {
    const int gid = blockIdx.x * 256 + threadIdx.x;
    if (gid >= NB * NPOINT * 128) return;
    const int c = gid & 127;
    const float a  = stats[A3OFF + c];
    const float cc = stats[C3OFF + c];
    const float v  = (a >= 0.f) ? maxbuf[gid] : minbuf[gid];
    outp[gid] = fmaxf(0.f, fmaf(a, v, cc));
}

// =====================================================================
extern "C" void kernel_launch(void* const* d_in, const int* in_sizes, int n_in,
                              void* d_out, int out_size, void* d_ws, size_t ws_size,
                              hipStream_t stream) {
    const float* xyz    = (const float*)d_in[0];
    const float* points = (const float*)d_in[1];
    const float* w1 = (const float*)d_in[2];
    const float* b1 = (const float*)d_in[3];
    const float* g1 = (const float*)d_in[4];
    const float* bt1 = (const float*)d_in[5];
    const float* w2 = (const float*)d_in[6];
    const float* b2 = (const float*)d_in[7];
    const float* g2 = (const float*)d_in[8];
    const float* bt2 = (const float*)d_in[9];
    const float* w3 = (const float*)d_in[10];
    const float* b3 = (const float*)d_in[11];
    const float* g3 = (const float*)d_in[12];
    const float* bt3 = (const float*)d_in[13];

    float* out_newxyz = (float*)d_out;
    float* out_newpts = (float*)d_out + NB * NPOINT * 3;

    char* ws = (char*)d_ws;
    if (ws_size < SMALL_TOTAL) return;  // cannot run at all

    int*   gidx   = (int*)(ws + OFF_GIDX);
    float* stats  = (float*)(ws + OFF_STATS);
    float* maxbuf = (float*)(ws + OFF_MAX);
    float* minbuf = (float*)(ws + OFF_MIN);
    unsigned short* y2bf = (unsigned short*)(ws + OFF_Y2BF);
    unsigned short* y1bf = (unsigned short*)(ws + OFF_Y1BF);
    const bool med  = (ws_size >= MED_TOTAL);
    const bool big  = (ws_size >= BIG_TOTAL);
    const bool big2 = (ws_size >= BIG2_TOTAL);

    hipMemsetAsync(stats, 0, 65536, stream);

    fps_kernel<<<NB, 256, 0, stream>>>(xyz, out_newxyz);
    query_kernel<<<(NB * NPOINT * 64) / 256, 256, 0, stream>>>(xyz, out_newxyz, gidx);
    if (big2) {
        pass1_kernel<true><<<NROWS / 64, 256, 0, stream>>>(xyz, points, out_newxyz, gidx,
                                                           w1, b1, stats, y1bf);
        pass2big_kernel<<<NROWS / 64, 256, 0, stream>>>(y1bf, g1, bt1, w2, b2, stats, y2bf);
        pass3big_kernel<<<NROWS / 64, 256, 0, stream>>>(y2bf, g2, bt2, w3, b3,
                                                        stats, maxbuf, minbuf);
        derive3_kernel<<<1, 128, 0, stream>>>(g3, bt3, stats);
        final_kernel<<<(NB * NPOINT * 128) / 256, 256, 0, stream>>>(maxbuf, minbuf, stats, out_newpts);
    } else if (big) {
        pass1_kernel<false><<<NROWS / 64, 256, 0, stream>>>(xyz, points, out_newxyz, gidx,
                                                            w1, b1, stats, y1bf);
        pass2_kernel<true><<<NROWS / 64, 256, 0, stream>>>(xyz, points, out_newxyz, gidx,
                                                           w1, b1, g1, bt1, w2, b2, stats, y2bf);
        pass3big_kernel<<<NROWS / 64, 256, 0, stream>>>(y2bf, g2, bt2, w3, b3,
                                                        stats, maxbuf, minbuf);
        derive3_kernel<<<1, 128, 0, stream>>>(g3, bt3, stats);
        final_kernel<<<(NB * NPOINT * 128) / 256, 256, 0, stream>>>(maxbuf, minbuf, stats, out_newpts);
    } else if (med) {
        pass1_kernel<false><<<NROWS / 64, 256, 0, stream>>>(xyz, points, out_newxyz, gidx,
                                                            w1, b1, stats, y1bf);
        pass2_kernel<false><<<NROWS / 64, 256, 0, stream>>>(xyz, points, out_newxyz, gidx,
                                                            w1, b1, g1, bt1, w2, b2, stats, y2bf);
        pass3_kernel<true><<<NROWS / 64, 256, 0, stream>>>(xyz, points, out_newxyz, gidx,
                                                           w1, b1, g1, bt1, w2, b2, g2, bt2,
                                                           w3, b3, stats, maxbuf, minbuf);
        derive3_kernel<<<1, 128, 0, stream>>>(g3, bt3, stats);
        final_kernel<<<(NB * NPOINT * 128) / 256, 256, 0, stream>>>(maxbuf, minbuf, stats, out_newpts);
    } else {
        pass1_kernel<false><<<NROWS / 64, 256, 0, stream>>>(xyz, points, out_newxyz, gidx,
                                                            w1, b1, stats, y1bf);
        pass2_kernel<false><<<NROWS / 64, 256, 0, stream>>>(xyz, points, out_newxyz, gidx,
                                                            w1, b1, g1, bt1, w2, b2, stats, y2bf);
        pass3_kernel<false><<<NROWS / 64, 256, 0, stream>>>(xyz, points, out_newxyz, gidx,
                                                            w1, b1, g1, bt1, w2, b2, g2, bt2,
                                                            w3, b3, stats, maxbuf, minbuf);
        pass4_kernel<<<NROWS / 64, 256, 0, stream>>>(xyz, points, out_newxyz, gidx,
                                                     w1, b1, g1, bt1, w2, b2, g2, bt2,
                                                     w3, b3, g3, bt3, stats, out_newpts);
    }
}

// Round 16
// 965.647 us; speedup vs baseline: 1.4482x; 1.0917x over previous
//
#include <hip/hip_runtime.h>
#include <cstdint>

#define NB 16
#define NN 4096
#define ND 64
#define NPOINT 1024
#define NSAMPLE 32
#define NROWS (NB * NPOINT * NSAMPLE)   // 524288 rows through the MLP
#define BN_EPS 1e-5f
#define NSLOT 32
#define LD 68                            // LDS tile leading dim (rows+pad)

// ---------------- ws layout (bytes) ----------------
#define OFF_GIDX   0
#define OFF_STATS  (2 * 1024 * 1024)
#define OFF_MAX    (OFF_STATS + 131072)
#define OFF_MIN    (OFF_MAX + 8388608)
#define MED_TOTAL  ((size_t)OFF_MIN + 8388608)       // ~18.1 MB
#define SMALL_TOTAL ((size_t)OFF_MAX)                // ~2.1 MB
#define OFF_Y2BF   MED_TOTAL                         // bf16 y2: 64 MB
#define BIG_TOTAL  (OFF_Y2BF + (size_t)NROWS * 64 * 2)    // ~82.1 MB
#define OFF_Y1BF   BIG_TOTAL                         // bf16 y1: 64 MB
#define BIG2_TOTAL (OFF_Y1BF + (size_t)NROWS * 64 * 2)    // ~146.2 MB

// stats area float offsets
#define S1SUM 0
#define S1SQ  2048
#define S2SUM 4096
#define S2SQ  6144
#define S3SUM 8192
#define S3SQ  12288
#define A3OFF 16384
#define C3OFF 16512

typedef float v2f __attribute__((ext_vector_type(2)));

__device__ __forceinline__ unsigned short f2bf(float f) {
    const unsigned u = __float_as_uint(f);
    return (unsigned short)((u + 0x7FFFu + ((u >> 16) & 1u)) >> 16);   // RNE
}
__device__ __forceinline__ float bf2f(unsigned short s) {
    return __uint_as_float(((unsigned)s) << 16);
}

// DPP-based wave64 fmax reduce step (ctrl/mask are template constants).
// bound_ctrl=true fills invalid lanes with 0 = fmax identity here (all >= 0).
template<int CTRL, int ROW_MASK>
__device__ __forceinline__ float dpp_fmax(float v) {
    const int mv = __builtin_amdgcn_update_dpp(0, __float_as_int(v), CTRL, ROW_MASK, 0xF, true);
    return fmaxf(v, __int_as_float(mv));
}

// =====================================================================
// K1: farthest point sampling. One block (256 thr = 4 waves) per batch.
// CONTIGUOUS 16 pts/lane (as 8 float2 pairs -> v_pk_* packed f32 VALU,
// 2 elems/instr, per-element IEEE rounding identical to scalar). Wave
// max via DPP; index via ballot+ctz+readlane. float4 parity slots; one
// barrier/iter. Exact np arithmetic; first-index tie-break:
//  - within lane: packed max tree + DESCENDING equality scan (smallest k)
//  - within wave: lowest tied lane (= smallest index, contiguity)
//  - across waves: sequential slot scan, strict > (lowest wave wins)
// =====================================================================
__global__ __launch_bounds__(256) void fps_kernel(const float* __restrict__ xyz,
                                                  float* __restrict__ out_newxyz) {
    __shared__ float pxyz[NN * 3];      // 48 KB
    __shared__ float4 slot[2][4];       // {val, x, y, z} per wave, parity-buffered
    const int b = blockIdx.x, tid = threadIdx.x;
    const int wave = tid >> 6, lane = tid & 63;
    const float* base = xyz + (size_t)b * NN * 3;

    for (int i = tid; i < NN * 3 / 4; i += 256)
        reinterpret_cast<float4*>(pxyz)[i] = reinterpret_cast<const float4*>(base)[i];
    __syncthreads();

    // registers: lane tid holds points p = tid*16 + {2j, 2j+1} packed
    v2f X2[8], Y2[8], Z2[8], D2[8];
#pragma unroll
    for (int j = 0; j < 8; ++j) {
        const int p = tid * 16 + 2 * j;
        X2[j].x = pxyz[3 * p + 0];  X2[j].y = pxyz[3 * (p + 1) + 0];
        Y2[j].x = pxyz[3 * p + 1];  Y2[j].y = pxyz[3 * (p + 1) + 1];
        Z2[j].x = pxyz[3 * p + 2];  Z2[j].y = pxyz[3 * (p + 1) + 2];
        D2[j].x = 1e10f;            D2[j].y = 1e10f;
    }

    float cx = pxyz[0], cy = pxyz[1], cz = pxyz[2];   // initial farthest = 0
    float* outb = out_newxyz + (size_t)b * NPOINT * 3;

    for (int it = 0; it < NPOINT; ++it) {
        if (tid == 0) {
            outb[it * 3 + 0] = cx;
            outb[it * 3 + 1] = cy;
            outb[it * 3 + 2] = cz;
        }
        const v2f cxx = {cx, cx}, cyy = {cy, cy}, czz = {cz, cz};
#pragma unroll
        for (int j = 0; j < 8; ++j) {
            const v2f dx = X2[j] - cxx;           // per-elem IEEE fsub
            const v2f dy = Y2[j] - cyy;
            const v2f dz = Z2[j] - czz;
            const v2f xx = dx * dx;               // per-elem IEEE fmul
            const v2f yy = dy * dy;
            const v2f zz = dz * dz;
            const v2f s  = (xx + yy) + zz;        // exact np order
            D2[j] = __builtin_elementwise_min(D2[j], s);
        }
        // in-lane max via packed tree
        v2f m = D2[0];
#pragma unroll
        for (int j = 1; j < 8; ++j) m = __builtin_elementwise_max(m, D2[j]);
        float bv = fmaxf(m.x, m.y);
        // smallest k achieving bv (descending scan: last write = smallest k)
        int bk = 0;
#pragma unroll
        for (int k = 15; k >= 0; --k) {
            const float dk = (k & 1) ? D2[k >> 1].y : D2[k >> 1].x;
            if (dk == bv) bk = k;
        }
        const int bi = tid * 16 + bk;
        // wave64 max reduce via DPP (VALU only, no LDS)
        float v = bv;
        v = dpp_fmax<0x111, 0xF>(v);   // row_shr:1
        v = dpp_fmax<0x112, 0xF>(v);   // row_shr:2
        v = dpp_fmax<0x114, 0xF>(v);   // row_shr:4
        v = dpp_fmax<0x118, 0xF>(v);   // row_shr:8  -> lane15 of each row = row max
        v = dpp_fmax<0x142, 0xA>(v);   // row_bcast:15 into rows 1,3
        v = dpp_fmax<0x143, 0xC>(v);   // row_bcast:31 into rows 2,3 -> lane63 = wave max
        const float wmax = __int_as_float(__builtin_amdgcn_readlane(__float_as_int(v), 63));
        const unsigned long long mask = __ballot(bv == wmax);
        const int src  = (int)__builtin_ctzll(mask);     // lowest tied lane
        const int widx = __builtin_amdgcn_readlane(bi, src);
        const int par = it & 1;
        if (lane == 0) {
            slot[par][wave] = make_float4(wmax, pxyz[3 * widx + 0],
                                                pxyz[3 * widx + 1],
                                                pxyz[3 * widx + 2]);
        }
        __syncthreads();
        float4 best = slot[par][0];
#pragma unroll
        for (int w = 1; w < 4; ++w) {
            const float4 s = slot[par][w];
            if (s.x > best.x) best = s;   // strict > : lowest wave wins ties
        }
        cx = best.y; cy = best.z; cz = best.w;
    }
}

// =====================================================================
// K2: query_ball_point. One wave per query; ordered prefix selection of
// first NSAMPLE idx with d^2 <= r^2. 2 chunks (128 pts) per loop iter.
// =====================================================================
__global__ __launch_bounds__(256) void query_kernel(const float* __restrict__ xyz,
                                                    const float* __restrict__ newxyz,
                                                    int* __restrict__ gidx) {
    const int gtid = blockIdx.x * 256 + threadIdx.x;
    const int q    = gtid >> 6;
    const int lane = threadIdx.x & 63;
    if (q >= NB * NPOINT) return;
    const int b = q >> 10;
    const float* xb = xyz + (size_t)b * NN * 3;
    const float cx = newxyz[q * 3 + 0];
    const float cy = newxyz[q * 3 + 1];
    const float cz = newxyz[q * 3 + 2];
    const float snew = __fadd_rn(__fadd_rn(__fmul_rn(cx, cx), __fmul_rn(cy, cy)),
                                 __fmul_rn(cz, cz));
    const float rsq = (float)(0.2 * 0.2);
    int* outq = gidx + (size_t)q * NSAMPLE;

    int count = 0, first = 0;
    for (int base = 0; base < NN; base += 128) {
        const int pA = base + lane, pB = base + 64 + lane;
        const float xA = xb[pA * 3 + 0], yA = xb[pA * 3 + 1], zA = xb[pA * 3 + 2];
        const float xB = xb[pB * 3 + 0], yB = xb[pB * 3 + 1], zB = xb[pB * 3 + 2];
        const float sxA = __fadd_rn(__fadd_rn(__fmul_rn(xA, xA), __fmul_rn(yA, yA)),
                                    __fmul_rn(zA, zA));
        const float sxB = __fadd_rn(__fadd_rn(__fmul_rn(xB, xB), __fmul_rn(yB, yB)),
                                    __fmul_rn(zB, zB));
        float dotA = __fmul_rn(cx, xA);
        dotA = fmaf(cy, yA, dotA);
        dotA = fmaf(cz, zA, dotA);
        float dotB = __fmul_rn(cx, xB);
        dotB = fmaf(cy, yB, dotB);
        dotB = fmaf(cz, zB, dotB);
        const float sqA = __fadd_rn(__fsub_rn(snew, __fadd_rn(dotA, dotA)), sxA);
        const float sqB = __fadd_rn(__fsub_rn(snew, __fadd_rn(dotB, dotB)), sxB);
        const bool qualA = !(sqA > rsq);
        const bool qualB = !(sqB > rsq);
        const unsigned long long maskA = __ballot(qualA);
        const unsigned long long maskB = __ballot(qualB);
        if (count == 0) {
            if (maskA)      first = base + (int)__builtin_ctzll(maskA);
            else if (maskB) first = base + 64 + (int)__builtin_ctzll(maskB);
        }
        const unsigned long long below = (1ull << lane) - 1ull;
        const int cA = __popcll(maskA);
        if (qualA) {
            const int pos = count + __popcll(maskA & below);
            if (pos < NSAMPLE) outq[pos] = pA;
        }
        if (qualB) {
            const int pos = count + cA + __popcll(maskB & below);
            if (pos < NSAMPLE) outq[pos] = pB;
        }
        count += cA + __popcll(maskB);
        if (count >= NSAMPLE) break;
    }
    if (count < NSAMPLE) {
        for (int pos = count + lane; pos < NSAMPLE; pos += 64) outq[pos] = first;
    }
}

// =====================================================================
// Shared device helpers for the 64-row tiled MLP passes.
// =====================================================================
__device__ __forceinline__ void stage64(const float* __restrict__ xyz,
                                        const float* __restrict__ points,
                                        const float* __restrict__ newxyz,
                                        const int* __restrict__ gidx,
                                        int row0, int tid, float* featT) {
    const int rl = tid >> 2, qd = tid & 3;
    const int R   = row0 + rl;
    const int grp = R >> 5;
    const int idx = gidx[R];
    const int b   = grp >> 10;
    const float* prow = points + ((size_t)b * NN + idx) * ND + qd * 16;
#pragma unroll
    for (int j = 0; j < 4; ++j) {
        const float4 v = *reinterpret_cast<const float4*>(prow + j * 4);
        const int k = 3 + qd * 16 + j * 4;
        featT[(k + 0) * LD + rl] = v.x;
        featT[(k + 1) * LD + rl] = v.y;
        featT[(k + 2) * LD + rl] = v.z;
        featT[(k + 3) * LD + rl] = v.w;
    }
    if (qd == 0) {
        const float* xr = xyz + ((size_t)b * NN + idx) * 3;
        const float* cr = newxyz + (size_t)grp * 3;
        featT[0 * LD + rl] = xr[0] - cr[0];
        featT[1 * LD + rl] = xr[1] - cr[1];
        featT[2 * LD + rl] = xr[2] - cr[2];
    }
}

__device__ __forceinline__ void fold64(const float* __restrict__ ssum,
                                       const float* __restrict__ ssq,
                                       const float* __restrict__ g,
                                       const float* __restrict__ bt,
                                       int tid, float* a_s, float* c_s) {
    if (tid < 64) {
        float s = 0.f, q = 0.f;
#pragma unroll
        for (int sl = 0; sl < NSLOT; ++sl) { s += ssum[sl * 64 + tid]; q += ssq[sl * 64 + tid]; }
        const float Ninv = 1.0f / (float)NROWS;
        const float mean = s * Ninv;
        const float var  = fmaf(-mean, mean, q * Ninv);
        const float a    = g[tid] * rsqrtf(var + BN_EPS);
        a_s[tid] = a;
        c_s[tid] = bt[tid] - mean * a;
    }
}

// y = inT @ w^T + b; out = relu(a*y + c), written transposed [64ch][LD]
template<int CIN>
__device__ __forceinline__ void mm_bnrelu(const float* __restrict__ w,
                                          const float* __restrict__ bias,
                                          const float* inT, float* outT,
                                          const float* a_s, const float* c_s, int tid) {
    const int c = tid & 63, rg = tid >> 6;
    float wr[CIN];
#pragma unroll
    for (int k = 0; k < CIN; ++k) wr[k] = w[c * CIN + k];
    const float bv = bias[c];
    const float av = a_s[c], cv = c_s[c];
#pragma unroll
    for (int bat = 0; bat < 2; ++bat) {
        const int rb = rg * 16 + bat * 8;
        float acc[8];
#pragma unroll
        for (int j = 0; j < 8; ++j) acc[j] = bv;
#pragma unroll
        for (int k = 0; k < CIN; ++k) {
            float f[8];
            *reinterpret_cast<float4*>(&f[0]) = *reinterpret_cast<const float4*>(&inT[k * LD + rb]);
            *reinterpret_cast<float4*>(&f[4]) = *reinterpret_cast<const float4*>(&inT[k * LD + rb + 4]);
            const float wv = wr[k];
#pragma unroll
            for (int j = 0; j < 8; ++j) acc[j] = fmaf(f[j], wv, acc[j]);
        }
        float o[8];
#pragma unroll
        for (int j = 0; j < 8; ++j) o[j] = fmaxf(0.f, fmaf(av, acc[j], cv));
        *reinterpret_cast<float4*>(&outT[c * LD + rb])     = *reinterpret_cast<float4*>(&o[0]);
        *reinterpret_cast<float4*>(&outT[c * LD + rb + 4]) = *reinterpret_cast<float4*>(&o[4]);
    }
}

// =====================================================================
// P1: stats for layer1 (Σy1, Σy1²). If ST, store raw y1 (pre-BN) bf16.
// =====================================================================
template<bool ST>
__global__ __launch_bounds__(256) void pass1_kernel(
    const float* __restrict__ xyz, const float* __restrict__ points,
    const float* __restrict__ newxyz, const int* __restrict__ gidx,
    const float* __restrict__ w1, const float* __restrict__ b1,
    float* __restrict__ stats, unsigned short* __restrict__ y1bf) {
    __shared__ float featT[67 * LD];
    __shared__ float red[4][64], redq[4][64];
    const int tid = threadIdx.x, blk = blockIdx.x;
    stage64(xyz, points, newxyz, gidx, blk * 64, tid, featT);
    __syncthreads();
    const int c = tid & 63, rg = tid >> 6;
    float wr[67];
#pragma unroll
    for (int k = 0; k < 67; ++k) wr[k] = w1[c * 67 + k];
    const float bv = b1[c];
    float ssum = 0.f, ssq = 0.f;
#pragma unroll
    for (int bat = 0; bat < 2; ++bat) {
        const int rb = rg * 16 + bat * 8;
        float acc[8];
#pragma unroll
        for (int j = 0; j < 8; ++j) acc[j] = bv;
#pragma unroll
        for (int k = 0; k < 67; ++k) {
            float f[8];
            *reinterpret_cast<float4*>(&f[0]) = *reinterpret_cast<const float4*>(&featT[k * LD + rb]);
            *reinterpret_cast<float4*>(&f[4]) = *reinterpret_cast<const float4*>(&featT[k * LD + rb + 4]);
            const float wv = wr[k];
#pragma unroll
            for (int j = 0; j < 8; ++j) acc[j] = fmaf(f[j], wv, acc[j]);
        }
        if (ST) {
            unsigned short o[8];
#pragma unroll
            for (int j = 0; j < 8; ++j) o[j] = f2bf(acc[j]);
            *reinterpret_cast<uint4*>(&y1bf[(size_t)blk * 4096 + c * 64 + rb]) =
                *reinterpret_cast<uint4*>(o);
        }
#pragma unroll
        for (int j = 0; j < 8; ++j) { ssum += acc[j]; ssq = fmaf(acc[j], acc[j], ssq); }
    }
    red[rg][c] = ssum;
    redq[rg][c] = ssq;
    __syncthreads();
    if (tid < 64) {
        const float s = red[0][tid] + red[1][tid] + red[2][tid] + red[3][tid];
        const float q = redq[0][tid] + redq[1][tid] + redq[2][tid] + redq[3][tid];
        const int slot = blk & (NSLOT - 1);
        atomicAdd(&stats[S1SUM + slot * 64 + tid], s);
        atomicAdd(&stats[S1SQ + slot * 64 + tid], q);
    }
}

// =====================================================================
// P2big: load bf16 y1 tile, t1 = relu(bn1(y1)), y2 matmul, store y2 bf16
// + stats2. No gather, no layer-1 recompute.
// =====================================================================
__global__ __launch_bounds__(256) void pass2big_kernel(
    const unsigned short* __restrict__ y1bf,
    const float* __restrict__ g1, const float* __restrict__ bt1,
    const float* __restrict__ w2, const float* __restrict__ b2,
    float* __restrict__ stats, unsigned short* __restrict__ y2bf) {
    __shared__ float t1T[64 * LD];
    __shared__ float a1s[64], c1s[64];
    __shared__ float red[4][64], redq[4][64];
    const int tid = threadIdx.x, blk = blockIdx.x;
    fold64(stats + S1SUM, stats + S1SQ, g1, bt1, tid, a1s, c1s);
    __syncthreads();
    {
        const int cch = tid >> 2, r0 = (tid & 3) * 16;
        const float a1 = a1s[cch], c1 = c1s[cch];
        const uint4 u0 = *reinterpret_cast<const uint4*>(&y1bf[(size_t)blk * 4096 + cch * 64 + r0]);
        const uint4 u1 = *reinterpret_cast<const uint4*>(&y1bf[(size_t)blk * 4096 + cch * 64 + r0 + 8]);
        const unsigned short* us0 = reinterpret_cast<const unsigned short*>(&u0);
        const unsigned short* us1 = reinterpret_cast<const unsigned short*>(&u1);
#pragma unroll
        for (int j = 0; j < 8; ++j) {
            t1T[cch * LD + r0 + j]     = fmaxf(0.f, fmaf(a1, bf2f(us0[j]), c1));
            t1T[cch * LD + r0 + 8 + j] = fmaxf(0.f, fmaf(a1, bf2f(us1[j]), c1));
        }
    }
    __syncthreads();
    const int c = tid & 63, rg = tid >> 6;
    float wr[64];
#pragma unroll
    for (int k = 0; k < 64; ++k) wr[k] = w2[c * 64 + k];
    const float bv = b2[c];
    float ssum = 0.f, ssq = 0.f;
#pragma unroll
    for (int bat = 0; bat < 2; ++bat) {
        const int rb = rg * 16 + bat * 8;
        float acc[8];
#pragma unroll
        for (int j = 0; j < 8; ++j) acc[j] = bv;
#pragma unroll
        for (int k = 0; k < 64; ++k) {
            float f[8];
            *reinterpret_cast<float4*>(&f[0]) = *reinterpret_cast<const float4*>(&t1T[k * LD + rb]);
            *reinterpret_cast<float4*>(&f[4]) = *reinterpret_cast<const float4*>(&t1T[k * LD + rb + 4]);
            const float wv = wr[k];
#pragma unroll
            for (int j = 0; j < 8; ++j) acc[j] = fmaf(f[j], wv, acc[j]);
        }
        {
            unsigned short o[8];
#pragma unroll
            for (int j = 0; j < 8; ++j) o[j] = f2bf(acc[j]);
            *reinterpret_cast<uint4*>(&y2bf[(size_t)blk * 4096 + c * 64 + rb]) =
                *reinterpret_cast<uint4*>(o);
        }
#pragma unroll
        for (int j = 0; j < 8; ++j) { ssum += acc[j]; ssq = fmaf(acc[j], acc[j], ssq); }
    }
    red[rg][c] = ssum;
    redq[rg][c] = ssq;
    __syncthreads();
    if (tid < 64) {
        const float s = red[0][tid] + red[1][tid] + red[2][tid] + red[3][tid];
        const float q = redq[0][tid] + redq[1][tid] + redq[2][tid] + redq[3][tid];
        const int slot = blk & (NSLOT - 1);
        atomicAdd(&stats[S2SUM + slot * 64 + tid], s);
        atomicAdd(&stats[S2SQ + slot * 64 + tid], q);
    }
}

// =====================================================================
// P2: full recompute variant. If ST stores y2 bf16.
// =====================================================================
template<bool ST>
__global__ __launch_bounds__(256) void pass2_kernel(
    const float* __restrict__ xyz, const float* __restrict__ points,
    const float* __restrict__ newxyz, const int* __restrict__ gidx,
    const float* __restrict__ w1, const float* __restrict__ b1,
    const float* __restrict__ g1, const float* __restrict__ bt1,
    const float* __restrict__ w2, const float* __restrict__ b2,
    float* __restrict__ stats, unsigned short* __restrict__ y2bf) {
    __shared__ float featT[67 * LD];
    __shared__ float t1T[64 * LD];
    __shared__ float a1s[64], c1s[64];
    __shared__ float red[4][64], redq[4][64];
    const int tid = threadIdx.x, blk = blockIdx.x;
    fold64(stats + S1SUM, stats + S1SQ, g1, bt1, tid, a1s, c1s);
    stage64(xyz, points, newxyz, gidx, blk * 64, tid, featT);
    __syncthreads();
    mm_bnrelu<67>(w1, b1, featT, t1T, a1s, c1s, tid);
    __syncthreads();
    const int c = tid & 63, rg = tid >> 6;
    float wr[64];
#pragma unroll
    for (int k = 0; k < 64; ++k) wr[k] = w2[c * 64 + k];
    const float bv = b2[c];
    float ssum = 0.f, ssq = 0.f;
#pragma unroll
    for (int bat = 0; bat < 2; ++bat) {
        const int rb = rg * 16 + bat * 8;
        float acc[8];
#pragma unroll
        for (int j = 0; j < 8; ++j) acc[j] = bv;
#pragma unroll
        for (int k = 0; k < 64; ++k) {
            float f[8];
            *reinterpret_cast<float4*>(&f[0]) = *reinterpret_cast<const float4*>(&t1T[k * LD + rb]);
            *reinterpret_cast<float4*>(&f[4]) = *reinterpret_cast<const float4*>(&t1T[k * LD + rb + 4]);
            const float wv = wr[k];
#pragma unroll
            for (int j = 0; j < 8; ++j) acc[j] = fmaf(f[j], wv, acc[j]);
        }
        if (ST) {
            unsigned short o[8];
#pragma unroll
            for (int j = 0; j < 8; ++j) o[j] = f2bf(acc[j]);
            *reinterpret_cast<uint4*>(&y2bf[(size_t)blk * 4096 + c * 64 + rb]) =
                *reinterpret_cast<uint4*>(o);
        }
#pragma unroll
        for (int j = 0; j < 8; ++j) { ssum += acc[j]; ssq = fmaf(acc[j], acc[j], ssq); }
    }
    red[rg][c] = ssum;
    redq[rg][c] = ssq;
    __syncthreads();
    if (tid < 64) {
        const float s = red[0][tid] + red[1][tid] + red[2][tid] + red[3][tid];
        const float q = redq[0][tid] + redq[1][tid] + redq[2][tid] + redq[3][tid];
        const int slot = blk & (NSLOT - 1);
        atomicAdd(&stats[S2SUM + slot * 64 + tid], s);
        atomicAdd(&stats[S2SQ + slot * 64 + tid], q);
    }
}

// =====================================================================
// P3big: load bf16 y2 tile, t2 = relu(bn2(y2)), y3 matmul (2-ch blocked),
// stats3 + per-(b,s,c) max/min.
// =====================================================================
__global__ __launch_bounds__(256) void pass3big_kernel(
    const unsigned short* __restrict__ y2bf,
    const float* __restrict__ g2, const float* __restrict__ bt2,
    const float* __restrict__ w3, const float* __restrict__ b3,
    float* __restrict__ stats, float* __restrict__ maxbuf, float* __restrict__ minbuf) {
    __shared__ float t2T[64 * LD];
    __shared__ float a2s[64], c2s[64];
    __shared__ float redM[4][128], redm[4][128], redS[4][128], redQ[4][128];
    const int tid = threadIdx.x, blk = blockIdx.x;
    fold64(stats + S2SUM, stats + S2SQ, g2, bt2, tid, a2s, c2s);
    __syncthreads();
    {
        const int cch = tid >> 2, r0 = (tid & 3) * 16;
        const float a2 = a2s[cch], c2 = c2s[cch];
        const uint4 u0 = *reinterpret_cast<const uint4*>(&y2bf[(size_t)blk * 4096 + cch * 64 + r0]);
        const uint4 u1 = *reinterpret_cast<const uint4*>(&y2bf[(size_t)blk * 4096 + cch * 64 + r0 + 8]);
        const unsigned short* us0 = reinterpret_cast<const unsigned short*>(&u0);
        const unsigned short* us1 = reinterpret_cast<const unsigned short*>(&u1);
#pragma unroll
        for (int j = 0; j < 8; ++j) {
            t2T[cch * LD + r0 + j]     = fmaxf(0.f, fmaf(a2, bf2f(us0[j]), c2));
            t2T[cch * LD + r0 + 8 + j] = fmaxf(0.f, fmaf(a2, bf2f(us1[j]), c2));
        }
    }
    __syncthreads();

    const int c0 = tid & 63, rg2 = tid >> 6;
    const int rb = rg2 * 16;
    float acc0[16], acc1[16];
    const float bv0 = b3[c0], bv1 = b3[c0 + 64];
#pragma unroll
    for (int j = 0; j < 16; ++j) { acc0[j] = bv0; acc1[j] = bv1; }
    for (int half = 0; half < 2; ++half) {
        float wr0[32], wr1[32];
#pragma unroll
        for (int k = 0; k < 32; ++k) {
            wr0[k] = w3[c0 * 64 + half * 32 + k];
            wr1[k] = w3[(c0 + 64) * 64 + half * 32 + k];
        }
#pragma unroll
        for (int k = 0; k < 32; ++k) {
            const int kk = half * 32 + k;
            float f[16];
            *reinterpret_cast<float4*>(&f[0])  = *reinterpret_cast<const float4*>(&t2T[kk * LD + rb]);
            *reinterpret_cast<float4*>(&f[4])  = *reinterpret_cast<const float4*>(&t2T[kk * LD + rb + 4]);
            *reinterpret_cast<float4*>(&f[8])  = *reinterpret_cast<const float4*>(&t2T[kk * LD + rb + 8]);
            *reinterpret_cast<float4*>(&f[12]) = *reinterpret_cast<const float4*>(&t2T[kk * LD + rb + 12]);
            const float w0 = wr0[k], w1v = wr1[k];
#pragma unroll
            for (int j = 0; j < 16; ++j) {
                acc0[j] = fmaf(f[j], w0, acc0[j]);
                acc1[j] = fmaf(f[j], w1v, acc1[j]);
            }
        }
    }
    float maxv0 = -3.4e38f, minv0 = 3.4e38f, ssum0 = 0.f, ssq0 = 0.f;
    float maxv1 = -3.4e38f, minv1 = 3.4e38f, ssum1 = 0.f, ssq1 = 0.f;
#pragma unroll
    for (int j = 0; j < 16; ++j) {
        maxv0 = fmaxf(maxv0, acc0[j]); minv0 = fminf(minv0, acc0[j]);
        ssum0 += acc0[j]; ssq0 = fmaf(acc0[j], acc0[j], ssq0);
        maxv1 = fmaxf(maxv1, acc1[j]); minv1 = fminf(minv1, acc1[j]);
        ssum1 += acc1[j]; ssq1 = fmaf(acc1[j], acc1[j], ssq1);
    }
    redM[rg2][c0] = maxv0; redM[rg2][c0 + 64] = maxv1;
    redm[rg2][c0] = minv0; redm[rg2][c0 + 64] = minv1;
    redS[rg2][c0] = ssum0; redS[rg2][c0 + 64] = ssum1;
    redQ[rg2][c0] = ssq0;  redQ[rg2][c0 + 64] = ssq1;
    __syncthreads();
    {
        const int g2i = tid >> 7, cc = tid & 127;
        const int g = blk * 2 + g2i;
        maxbuf[(size_t)g * 128 + cc] = fmaxf(redM[2 * g2i][cc], redM[2 * g2i + 1][cc]);
        minbuf[(size_t)g * 128 + cc] = fminf(redm[2 * g2i][cc], redm[2 * g2i + 1][cc]);
    }
    if (tid < 128) {
        const float s = (redS[0][tid] + redS[1][tid]) + (redS[2][tid] + redS[3][tid]);
        const float q = (redQ[0][tid] + redQ[1][tid]) + (redQ[2][tid] + redQ[3][tid]);
        const int slot = blk & (NSLOT - 1);
        atomicAdd(&stats[S3SUM + slot * 128 + tid], s);
        atomicAdd(&stats[S3SQ + slot * 128 + tid], q);
    }
}

// =====================================================================
// P3: full recompute variant (med/small ws). Stats3 + (MM) max/min.
// =====================================================================
template<bool MM>
__global__ __launch_bounds__(256) void pass3_kernel(
    const float* __restrict__ xyz, const float* __restrict__ points,
    const float* __restrict__ newxyz, const int* __restrict__ gidx,
    const float* __restrict__ w1, const float* __restrict__ b1,
    const float* __restrict__ g1, const float* __restrict__ bt1,
    const float* __restrict__ w2, const float* __restrict__ b2,
    const float* __restrict__ g2, const float* __restrict__ bt2,
    const float* __restrict__ w3, const float* __restrict__ b3,
    float* __restrict__ stats, float* __restrict__ maxbuf, float* __restrict__ minbuf) {
    __shared__ float bufA[67 * LD];
    __shared__ float t1T[64 * LD];
    __shared__ float a1s[64], c1s[64], a2s[64], c2s[64];
    __shared__ float redM[4][128], redm[4][128], redS[4][128], redQ[4][128];
    const int tid = threadIdx.x, blk = blockIdx.x;
    fold64(stats + S1SUM, stats + S1SQ, g1, bt1, tid, a1s, c1s);
    fold64(stats + S2SUM, stats + S2SQ, g2, bt2, tid, a2s, c2s);
    stage64(xyz, points, newxyz, gidx, blk * 64, tid, bufA);
    __syncthreads();
    mm_bnrelu<67>(w1, b1, bufA, t1T, a1s, c1s, tid);
    __syncthreads();
    mm_bnrelu<64>(w2, b2, t1T, bufA, a2s, c2s, tid);
    __syncthreads();

    const int c0 = tid & 63, rg2 = tid >> 6;
    const int rb = rg2 * 16;
    float acc0[16], acc1[16];
    const float bv0 = b3[c0], bv1 = b3[c0 + 64];
#pragma unroll
    for (int j = 0; j < 16; ++j) { acc0[j] = bv0; acc1[j] = bv1; }
    for (int half = 0; half < 2; ++half) {
        float wr0[32], wr1[32];
#pragma unroll
        for (int k = 0; k < 32; ++k) {
            wr0[k] = w3[c0 * 64 + half * 32 + k];
            wr1[k] = w3[(c0 + 64) * 64 + half * 32 + k];
        }
#pragma unroll
        for (int k = 0; k < 32; ++k) {
            const int kk = half * 32 + k;
            float f[16];
            *reinterpret_cast<float4*>(&f[0])  = *reinterpret_cast<const float4*>(&bufA[kk * LD + rb]);
            *reinterpret_cast<float4*>(&f[4])  = *reinterpret_cast<const float4*>(&bufA[kk * LD + rb + 4]);
            *reinterpret_cast<float4*>(&f[8])  = *reinterpret_cast<const float4*>(&bufA[kk * LD + rb + 8]);
            *reinterpret_cast<float4*>(&f[12]) = *reinterpret_cast<const float4*>(&bufA[kk * LD + rb + 12]);
            const float w0 = wr0[k], w1v = wr1[k];
#pragma unroll
            for (int j = 0; j < 16; ++j) {
                acc0[j] = fmaf(f[j], w0, acc0[j]);
                acc1[j] = fmaf(f[j], w1v, acc1[j]);
            }
        }
    }
    float maxv0 = -3.4e38f, minv0 = 3.4e38f, ssum0 = 0.f, ssq0 = 0.f;
    float maxv1 = -3.4e38f, minv1 = 3.4e38f, ssum1 = 0.f, ssq1 = 0.f;
#pragma unroll
    for (int j = 0; j < 16; ++j) {
        maxv0 = fmaxf(maxv0, acc0[j]); minv0 = fminf(minv0, acc0[j]);
        ssum0 += acc0[j]; ssq0 = fmaf(acc0[j], acc0[j], ssq0);
        maxv1 = fmaxf(maxv1, acc1[j]); minv1 = fminf(minv1, acc1[j]);
        ssum1 += acc1[j]; ssq1 = fmaf(acc1[j], acc1[j], ssq1);
    }
    redM[rg2][c0] = maxv0; redM[rg2][c0 + 64] = maxv1;
    redm[rg2][c0] = minv0; redm[rg2][c0 + 64] = minv1;
    redS[rg2][c0] = ssum0; redS[rg2][c0 + 64] = ssum1;
    redQ[rg2][c0] = ssq0;  redQ[rg2][c0 + 64] = ssq1;
    __syncthreads();
    if (MM) {
        const int g2i = tid >> 7, cc = tid & 127;
        const int g = blk * 2 + g2i;
        maxbuf[(size_t)g * 128 + cc] = fmaxf(redM[2 * g2i][cc], redM[2 * g2i + 1][cc]);
        minbuf[(size_t)g * 128 + cc] = fminf(redm[2 * g2i][cc], redm[2 * g2i + 1][cc]);
    }
    if (tid < 128) {
        const float s = (redS[0][tid] + redS[1][tid]) + (redS[2][tid] + redS[3][tid]);
        const float q = (redQ[0][tid] + redQ[1][tid]) + (redQ[2][tid] + redQ[3][tid]);
        const int slot = blk & (NSLOT - 1);
        atomicAdd(&stats[S3SUM + slot * 128 + tid], s);
        atomicAdd(&stats[S3SQ + slot * 128 + tid], q);
    }
}

// =====================================================================
// P4 (small-ws fallback): full recompute + BN3 + ReLU + maxpool -> out.
// =====================================================================
__global__ __launch_bounds__(256) void pass4_kernel(
    const float* __restrict__ xyz, const float* __restrict__ points,
    const float* __restrict__ newxyz, const int* __restrict__ gidx,
    const float* __restrict__ w1, const float* __restrict__ b1,
    const float* __restrict__ g1, const float* __restrict__ bt1,
    const float* __restrict__ w2, const float* __restrict__ b2,
    const float* __restrict__ g2, const float* __restrict__ bt2,
    const float* __restrict__ w3, const float* __restrict__ b3,
    const float* __restrict__ g3, const float* __restrict__ bt3,
    const float* __restrict__ stats, float* __restrict__ outp) {
    __shared__ float bufA[67 * LD];
    __shared__ float t1T[64 * LD];
    __shared__ float a1s[64], c1s[64], a2s[64], c2s[64];
    __shared__ float a3s[128], c3s[128];
    const int tid = threadIdx.x, blk = blockIdx.x;
    fold64(stats + S1SUM, stats + S1SQ, g1, bt1, tid, a1s, c1s);
    fold64(stats + S2SUM, stats + S2SQ, g2, bt2, tid, a2s, c2s);
    if (tid < 128) {
        float s = 0.f, q = 0.f;
#pragma unroll
        for (int sl = 0; sl < NSLOT; ++sl) { s += stats[S3SUM + sl * 128 + tid]; q += stats[S3SQ + sl * 128 + tid]; }
        const float Ninv = 1.0f / (float)NROWS;
        const float mean = s * Ninv;
        const float var  = fmaf(-mean, mean, q * Ninv);
        const float a    = g3[tid] * rsqrtf(var + BN_EPS);
        a3s[tid] = a;
        c3s[tid] = bt3[tid] - mean * a;
    }
    stage64(xyz, points, newxyz, gidx, blk * 64, tid, bufA);
    __syncthreads();
    mm_bnrelu<67>(w1, b1, bufA, t1T, a1s, c1s, tid);
    __syncthreads();
    mm_bnrelu<64>(w2, b2, t1T, bufA, a2s, c2s, tid);
    __syncthreads();

    const int c2 = tid & 127, rg2 = tid >> 7;
    float wr[64];
#pragma unroll
    for (int k = 0; k < 64; ++k) wr[k] = w3[c2 * 64 + k];
    const float bv = b3[c2];
    const float av = a3s[c2], cv = c3s[c2];
    float maxv = -3.4e38f;
#pragma unroll
    for (int bat = 0; bat < 4; ++bat) {
        const int rb = rg2 * 32 + bat * 8;
        float acc[8];
#pragma unroll
        for (int j = 0; j < 8; ++j) acc[j] = bv;
#pragma unroll
        for (int k = 0; k < 64; ++k) {
            float f[8];
            *reinterpret_cast<float4*>(&f[0]) = *reinterpret_cast<const float4*>(&bufA[k * LD + rb]);
            *reinterpret_cast<float4*>(&f[4]) = *reinterpret_cast<const float4*>(&bufA[k * LD + rb + 4]);
            const float wv = wr[k];
#pragma unroll
            for (int j = 0; j < 8; ++j) acc[j] = fmaf(f[j], wv, acc[j]);
        }
#pragma unroll
        for (int j = 0; j < 8; ++j) maxv = fmaxf(maxv, fmaxf(0.f, fmaf(av, acc[j], cv)));
    }
    const int g = blk * 2 + rg2;
    outp[(size_t)g * 128 + c2] = maxv;
}

// =====================================================================
// derive3 + final
// =====================================================================
__global__ void derive3_kernel(const float* __restrict__ g3, const float* __restrict__ bt3,
                               float* __restrict__ stats) {
    const int c = threadIdx.x;  // 128
    float s = 0.f, q = 0.f;
#pragma unroll
    for (int sl = 0; sl < NSLOT; ++sl) { s += stats[S3SUM + sl * 128 + c]; q += stats[S3SQ + sl * 128 + c]; }
    const float Ninv = 1.0f / (float)NROWS;
    const float mean = s * Ninv;
    const float var  = fmaf(-mean, mean, q * Ninv);
    const float a    = g3[c] * rsqrtf(var + BN_EPS);
    stats[A3OFF + c] = a;
    stats[C3OFF + c] = bt3[c] - mean * a;
}

__global__ __launch_bounds__(256) void final_kernel(
    const float* __restrict__ maxbuf, const float* __restrict__ minbuf,
    const float* __restrict__ stats, float* __restrict__ outp) {
    const int gid = blockIdx.x * 256 + threadIdx.x;
    if (gid >= NB * NPOINT * 128) return;
    const int c = gid & 127;
    const float a  = stats[A3OFF + c];
    const float cc = stats[C3OFF + c];
    const float v  = (a >= 0.f) ? maxbuf[gid] : minbuf[gid];
    outp[gid] = fmaxf(0.f, fmaf(a, v, cc));
}

// =====================================================================
extern "C" void kernel_launch(void* const* d_in, const int* in_sizes, int n_in,
                              void* d_out, int out_size, void* d_ws, size_t ws_size,
                              hipStream_t stream) {
    const float* xyz    = (const float*)d_in[0];
    const float* points = (const float*)d_in[1];
    const float* w1 = (const float*)d_in[2];
    const float* b1 = (const float*)d_in[3];
    const float* g1 = (const float*)d_in[4];
    const float* bt1 = (const float*)d_in[5];
    const float* w2 = (const float*)d_in[6];
    const float* b2 = (const float*)d_in[7];
    const float* g2 = (const float*)d_in[8];
    const float* bt2 = (const float*)d_in[9];
    const float* w3 = (const float*)d_in[10];
    const float* b3 = (const float*)d_in[11];
    const float* g3 = (const float*)d_in[12];
    const float* bt3 = (const float*)d_in[13];

    float* out_newxyz = (float*)d_out;
    float* out_newpts = (float*)d_out + NB * NPOINT * 3;

    char* ws = (char*)d_ws;
    if (ws_size < SMALL_TOTAL) return;  // cannot run at all

    int*   gidx   = (int*)(ws + OFF_GIDX);
    float* stats  = (float*)(ws + OFF_STATS);
    float* maxbuf = (float*)(ws + OFF_MAX);
    float* minbuf = (float*)(ws + OFF_MIN);
    unsigned short* y2bf = (unsigned short*)(ws + OFF_Y2BF);
    unsigned short* y1bf = (unsigned short*)(ws + OFF_Y1BF);
    const bool med  = (ws_size >= MED_TOTAL);
    const bool big  = (ws_size >= BIG_TOTAL);
    const bool big2 = (ws_size >= BIG2_TOTAL);

    hipMemsetAsync(stats, 0, 65536, stream);

    fps_kernel<<<NB, 256, 0, stream>>>(xyz, out_newxyz);
    query_kernel<<<(NB * NPOINT * 64) / 256, 256, 0, stream>>>(xyz, out_newxyz, gidx);
    if (big2) {
        pass1_kernel<true><<<NROWS / 64, 256, 0, stream>>>(xyz, points, out_newxyz, gidx,
                                                           w1, b1, stats, y1bf);
        pass2big_kernel<<<NROWS / 64, 256, 0, stream>>>(y1bf, g1, bt1, w2, b2, stats, y2bf);
        pass3big_kernel<<<NROWS / 64, 256, 0, stream>>>(y2bf, g2, bt2, w3, b3,
                                                        stats, maxbuf, minbuf);
        derive3_kernel<<<1, 128, 0, stream>>>(g3, bt3, stats);
        final_kernel<<<(NB * NPOINT * 128) / 256, 256, 0, stream>>>(maxbuf, minbuf, stats, out_newpts);
    } else if (big) {
        pass1_kernel<false><<<NROWS / 64, 256, 0, stream>>>(xyz, points, out_newxyz, gidx,
                                                            w1, b1, stats, y1bf);
        pass2_kernel<true><<<NROWS / 64, 256, 0, stream>>>(xyz, points, out_newxyz, gidx,
                                                           w1, b1, g1, bt1, w2, b2, stats, y2bf);
        pass3big_kernel<<<NROWS / 64, 256, 0, stream>>>(y2bf, g2, bt2, w3, b3,
                                                        stats, maxbuf, minbuf);
        derive3_kernel<<<1, 128, 0, stream>>>(g3, bt3, stats);
        final_kernel<<<(NB * NPOINT * 128) / 256, 256, 0, stream>>>(maxbuf, minbuf, stats, out_newpts);
    } else if (med) {
        pass1_kernel<false><<<NROWS / 64, 256, 0, stream>>>(xyz, points, out_newxyz, gidx,
                                                            w1, b1, stats, y1bf);
        pass2_kernel<false><<<NROWS / 64, 256, 0, stream>>>(xyz, points, out_newxyz, gidx,
                                                            w1, b1, g1, bt1, w2, b2, stats, y2bf);
        pass3_kernel<true><<<NROWS / 64, 256, 0, stream>>>(xyz, points, out_newxyz, gidx,
                                                           w1, b1, g1, bt1, w2, b2, g2, bt2,
                                                           w3, b3, stats, maxbuf, minbuf);
        derive3_kernel<<<1, 128, 0, stream>>>(g3, bt3, stats);
        final_kernel<<<(NB * NPOINT * 128) / 256, 256, 0, stream>>>(maxbuf, minbuf, stats, out_newpts);
    } else {
        pass1_kernel<false><<<NROWS / 64, 256, 0, stream>>>(xyz, points, out_newxyz, gidx,
                                                            w1, b1, stats, y1bf);
        pass2_kernel<false><<<NROWS / 64, 256, 0, stream>>>(xyz, points, out_newxyz, gidx,
                                                            w1, b1, g1, bt1, w2, b2, stats, y2bf);
        pass3_kernel<false><<<NROWS / 64, 256, 0, stream>>>(xyz, points, out_newxyz, gidx,
                                                            w1, b1, g1, bt1, w2, b2, g2, bt2,
                                                            w3, b3, stats, maxbuf, minbuf);
        pass4_kernel<<<NROWS / 64, 256, 0, stream>>>(xyz, points, out_newxyz, gidx,
                                                     w1, b1, g1, bt1, w2, b2, g2, bt2,
                                                     w3, b3, g3, bt3, stats, out_newpts);
    }
}

// Round 17
// 957.124 us; speedup vs baseline: 1.4611x; 1.0089x over previous
//
#include <hip/hip_runtime.h>
#include <cstdint>

#define NB 16
#define NN 4096
#define ND 64
#define NPOINT 1024
#define NSAMPLE 32
#define NROWS (NB * NPOINT * NSAMPLE)   // 524288 rows through the MLP
#define BN_EPS 1e-5f
#define NSLOT 32
#define LD 68                            // LDS tile leading dim (rows+pad)

// ---------------- ws layout (bytes) ----------------
#define OFF_GIDX   0
#define OFF_STATS  (2 * 1024 * 1024)
#define OFF_MAX    (OFF_STATS + 131072)
#define OFF_MIN    (OFF_MAX + 8388608)
#define MED_TOTAL  ((size_t)OFF_MIN + 8388608)       // ~18.1 MB
#define SMALL_TOTAL ((size_t)OFF_MAX)                // ~2.1 MB
#define OFF_Y2BF   MED_TOTAL                         // bf16 y2: 64 MB
#define BIG_TOTAL  (OFF_Y2BF + (size_t)NROWS * 64 * 2)    // ~82.1 MB
#define OFF_Y1BF   BIG_TOTAL                         // bf16 y1: 64 MB
#define BIG2_TOTAL (OFF_Y1BF + (size_t)NROWS * 64 * 2)    // ~146.2 MB

// stats area float offsets
#define S1SUM 0
#define S1SQ  2048
#define S2SUM 4096
#define S2SQ  6144
#define S3SUM 8192
#define S3SQ  12288
#define A3OFF 16384
#define C3OFF 16512

typedef float v2f __attribute__((ext_vector_type(2)));

__device__ __forceinline__ unsigned short f2bf(float f) {
    const unsigned u = __float_as_uint(f);
    return (unsigned short)((u + 0x7FFFu + ((u >> 16) & 1u)) >> 16);   // RNE
}
__device__ __forceinline__ float bf2f(unsigned short s) {
    return __uint_as_float(((unsigned)s) << 16);
}

// DPP-based wave64 fmax reduce step (ctrl/mask are template constants).
// bound_ctrl=true fills invalid lanes with 0 = fmax identity here (all >= 0).
template<int CTRL, int ROW_MASK>
__device__ __forceinline__ float dpp_fmax(float v) {
    const int mv = __builtin_amdgcn_update_dpp(0, __float_as_int(v), CTRL, ROW_MASK, 0xF, true);
    return fmaxf(v, __int_as_float(mv));
}

// =====================================================================
// K1: farthest point sampling. One block (256 thr = 4 waves) per batch.
// CONTIGUOUS 16 pts/lane (as 8 float2 pairs -> v_pk_* packed f32 VALU).
// Wave max via DPP; index via ballot+ctz+readlane. float4 parity slots;
// one barrier/iter. Exact np arithmetic; first-index tie-break:
//  - within lane: packed max tree + DESCENDING equality scan (smallest k)
//  - within wave: lowest tied lane (= smallest index, contiguity)
//  - across waves: sequential slot scan, strict > (lowest wave wins)
// =====================================================================
__global__ __launch_bounds__(256) void fps_kernel(const float* __restrict__ xyz,
                                                  float* __restrict__ out_newxyz) {
    __shared__ float pxyz[NN * 3];      // 48 KB
    __shared__ float4 slot[2][4];       // {val, x, y, z} per wave, parity-buffered
    const int b = blockIdx.x, tid = threadIdx.x;
    const int wave = tid >> 6, lane = tid & 63;
    const float* base = xyz + (size_t)b * NN * 3;

    for (int i = tid; i < NN * 3 / 4; i += 256)
        reinterpret_cast<float4*>(pxyz)[i] = reinterpret_cast<const float4*>(base)[i];
    __syncthreads();

    // registers: lane tid holds points p = tid*16 + {2j, 2j+1} packed
    v2f X2[8], Y2[8], Z2[8], D2[8];
#pragma unroll
    for (int j = 0; j < 8; ++j) {
        const int p = tid * 16 + 2 * j;
        X2[j].x = pxyz[3 * p + 0];  X2[j].y = pxyz[3 * (p + 1) + 0];
        Y2[j].x = pxyz[3 * p + 1];  Y2[j].y = pxyz[3 * (p + 1) + 1];
        Z2[j].x = pxyz[3 * p + 2];  Z2[j].y = pxyz[3 * (p + 1) + 2];
        D2[j].x = 1e10f;            D2[j].y = 1e10f;
    }

    float cx = pxyz[0], cy = pxyz[1], cz = pxyz[2];   // initial farthest = 0
    float* outb = out_newxyz + (size_t)b * NPOINT * 3;

    for (int it = 0; it < NPOINT; ++it) {
        if (tid == 0) {
            outb[it * 3 + 0] = cx;
            outb[it * 3 + 1] = cy;
            outb[it * 3 + 2] = cz;
        }
        const v2f cxx = {cx, cx}, cyy = {cy, cy}, czz = {cz, cz};
#pragma unroll
        for (int j = 0; j < 8; ++j) {
            const v2f dx = X2[j] - cxx;           // per-elem IEEE fsub
            const v2f dy = Y2[j] - cyy;
            const v2f dz = Z2[j] - czz;
            const v2f xx = dx * dx;               // per-elem IEEE fmul
            const v2f yy = dy * dy;
            const v2f zz = dz * dz;
            const v2f s  = (xx + yy) + zz;        // exact np order
            D2[j] = __builtin_elementwise_min(D2[j], s);
        }
        // in-lane max via packed tree
        v2f m = D2[0];
#pragma unroll
        for (int j = 1; j < 8; ++j) m = __builtin_elementwise_max(m, D2[j]);
        float bv = fmaxf(m.x, m.y);
        // smallest k achieving bv (descending scan: last write = smallest k)
        int bk = 0;
#pragma unroll
        for (int k = 15; k >= 0; --k) {
            const float dk = (k & 1) ? D2[k >> 1].y : D2[k >> 1].x;
            if (dk == bv) bk = k;
        }
        const int bi = tid * 16 + bk;
        // wave64 max reduce via DPP (VALU only, no LDS)
        float v = bv;
        v = dpp_fmax<0x111, 0xF>(v);   // row_shr:1
        v = dpp_fmax<0x112, 0xF>(v);   // row_shr:2
        v = dpp_fmax<0x114, 0xF>(v);   // row_shr:4
        v = dpp_fmax<0x118, 0xF>(v);   // row_shr:8  -> lane15 of each row = row max
        v = dpp_fmax<0x142, 0xA>(v);   // row_bcast:15 into rows 1,3
        v = dpp_fmax<0x143, 0xC>(v);   // row_bcast:31 into rows 2,3 -> lane63 = wave max
        const float wmax = __int_as_float(__builtin_amdgcn_readlane(__float_as_int(v), 63));
        const unsigned long long mask = __ballot(bv == wmax);
        const int src  = (int)__builtin_ctzll(mask);     // lowest tied lane
        const int widx = __builtin_amdgcn_readlane(bi, src);
        const int par = it & 1;
        if (lane == 0) {
            slot[par][wave] = make_float4(wmax, pxyz[3 * widx + 0],
                                                pxyz[3 * widx + 1],
                                                pxyz[3 * widx + 2]);
        }
        __syncthreads();
        float4 best = slot[par][0];
#pragma unroll
        for (int w = 1; w < 4; ++w) {
            const float4 s = slot[par][w];
            if (s.x > best.x) best = s;   // strict > : lowest wave wins ties
        }
        cx = best.y; cy = best.z; cz = best.w;
    }
}

// =====================================================================
// K2: query_ball_point. One wave per query; ordered prefix selection of
// first NSAMPLE idx with d^2 <= r^2. 2 chunks (128 pts) per loop iter.
// =====================================================================
__global__ __launch_bounds__(256) void query_kernel(const float* __restrict__ xyz,
                                                    const float* __restrict__ newxyz,
                                                    int* __restrict__ gidx) {
    const int gtid = blockIdx.x * 256 + threadIdx.x;
    const int q    = gtid >> 6;
    const int lane = threadIdx.x & 63;
    if (q >= NB * NPOINT) return;
    const int b = q >> 10;
    const float* xb = xyz + (size_t)b * NN * 3;
    const float cx = newxyz[q * 3 + 0];
    const float cy = newxyz[q * 3 + 1];
    const float cz = newxyz[q * 3 + 2];
    const float snew = __fadd_rn(__fadd_rn(__fmul_rn(cx, cx), __fmul_rn(cy, cy)),
                                 __fmul_rn(cz, cz));
    const float rsq = (float)(0.2 * 0.2);
    int* outq = gidx + (size_t)q * NSAMPLE;

    int count = 0, first = 0;
    for (int base = 0; base < NN; base += 128) {
        const int pA = base + lane, pB = base + 64 + lane;
        const float xA = xb[pA * 3 + 0], yA = xb[pA * 3 + 1], zA = xb[pA * 3 + 2];
        const float xB = xb[pB * 3 + 0], yB = xb[pB * 3 + 1], zB = xb[pB * 3 + 2];
        const float sxA = __fadd_rn(__fadd_rn(__fmul_rn(xA, xA), __fmul_rn(yA, yA)),
                                    __fmul_rn(zA, zA));
        const float sxB = __fadd_rn(__fadd_rn(__fmul_rn(xB, xB), __fmul_rn(yB, yB)),
                                    __fmul_rn(zB, zB));
        float dotA = __fmul_rn(cx, xA);
        dotA = fmaf(cy, yA, dotA);
        dotA = fmaf(cz, zA, dotA);
        float dotB = __fmul_rn(cx, xB);
        dotB = fmaf(cy, yB, dotB);
        dotB = fmaf(cz, zB, dotB);
        const float sqA = __fadd_rn(__fsub_rn(snew, __fadd_rn(dotA, dotA)), sxA);
        const float sqB = __fadd_rn(__fsub_rn(snew, __fadd_rn(dotB, dotB)), sxB);
        const bool qualA = !(sqA > rsq);
        const bool qualB = !(sqB > rsq);
        const unsigned long long maskA = __ballot(qualA);
        const unsigned long long maskB = __ballot(qualB);
        if (count == 0) {
            if (maskA)      first = base + (int)__builtin_ctzll(maskA);
            else if (maskB) first = base + 64 + (int)__builtin_ctzll(maskB);
        }
        const unsigned long long below = (1ull << lane) - 1ull;
        const int cA = __popcll(maskA);
        if (qualA) {
            const int pos = count + __popcll(maskA & below);
            if (pos < NSAMPLE) outq[pos] = pA;
        }
        if (qualB) {
            const int pos = count + cA + __popcll(maskB & below);
            if (pos < NSAMPLE) outq[pos] = pB;
        }
        count += cA + __popcll(maskB);
        if (count >= NSAMPLE) break;
    }
    if (count < NSAMPLE) {
        for (int pos = count + lane; pos < NSAMPLE; pos += 64) outq[pos] = first;
    }
}

// =====================================================================
// Shared device helpers for the 64-row tiled MLP passes.
// =====================================================================
__device__ __forceinline__ void stage64(const float* __restrict__ xyz,
                                        const float* __restrict__ points,
                                        const float* __restrict__ newxyz,
                                        const int* __restrict__ gidx,
                                        int row0, int tid, float* featT) {
    const int rl = tid >> 2, qd = tid & 3;
    const int R   = row0 + rl;
    const int grp = R >> 5;
    const int idx = gidx[R];
    const int b   = grp >> 10;
    const float* prow = points + ((size_t)b * NN + idx) * ND + qd * 16;
#pragma unroll
    for (int j = 0; j < 4; ++j) {
        const float4 v = *reinterpret_cast<const float4*>(prow + j * 4);
        const int k = 3 + qd * 16 + j * 4;
        featT[(k + 0) * LD + rl] = v.x;
        featT[(k + 1) * LD + rl] = v.y;
        featT[(k + 2) * LD + rl] = v.z;
        featT[(k + 3) * LD + rl] = v.w;
    }
    if (qd == 0) {
        const float* xr = xyz + ((size_t)b * NN + idx) * 3;
        const float* cr = newxyz + (size_t)grp * 3;
        featT[0 * LD + rl] = xr[0] - cr[0];
        featT[1 * LD + rl] = xr[1] - cr[1];
        featT[2 * LD + rl] = xr[2] - cr[2];
    }
}

__device__ __forceinline__ void fold64(const float* __restrict__ ssum,
                                       const float* __restrict__ ssq,
                                       const float* __restrict__ g,
                                       const float* __restrict__ bt,
                                       int tid, float* a_s, float* c_s) {
    if (tid < 64) {
        float s = 0.f, q = 0.f;
#pragma unroll
        for (int sl = 0; sl < NSLOT; ++sl) { s += ssum[sl * 64 + tid]; q += ssq[sl * 64 + tid]; }
        const float Ninv = 1.0f / (float)NROWS;
        const float mean = s * Ninv;
        const float var  = fmaf(-mean, mean, q * Ninv);
        const float a    = g[tid] * rsqrtf(var + BN_EPS);
        a_s[tid] = a;
        c_s[tid] = bt[tid] - mean * a;
    }
}

// y = inT @ w^T + b; out = relu(a*y + c), written transposed [64ch][LD]
template<int CIN>
__device__ __forceinline__ void mm_bnrelu(const float* __restrict__ w,
                                          const float* __restrict__ bias,
                                          const float* inT, float* outT,
                                          const float* a_s, const float* c_s, int tid) {
    const int c = tid & 63, rg = tid >> 6;
    float wr[CIN];
#pragma unroll
    for (int k = 0; k < CIN; ++k) wr[k] = w[c * CIN + k];
    const float bv = bias[c];
    const float av = a_s[c], cv = c_s[c];
#pragma unroll
    for (int bat = 0; bat < 2; ++bat) {
        const int rb = rg * 16 + bat * 8;
        float acc[8];
#pragma unroll
        for (int j = 0; j < 8; ++j) acc[j] = bv;
#pragma unroll
        for (int k = 0; k < CIN; ++k) {
            float f[8];
            *reinterpret_cast<float4*>(&f[0]) = *reinterpret_cast<const float4*>(&inT[k * LD + rb]);
            *reinterpret_cast<float4*>(&f[4]) = *reinterpret_cast<const float4*>(&inT[k * LD + rb + 4]);
            const float wv = wr[k];
#pragma unroll
            for (int j = 0; j < 8; ++j) acc[j] = fmaf(f[j], wv, acc[j]);
        }
        float o[8];
#pragma unroll
        for (int j = 0; j < 8; ++j) o[j] = fmaxf(0.f, fmaf(av, acc[j], cv));
        *reinterpret_cast<float4*>(&outT[c * LD + rb])     = *reinterpret_cast<float4*>(&o[0]);
        *reinterpret_cast<float4*>(&outT[c * LD + rb + 4]) = *reinterpret_cast<float4*>(&o[4]);
    }
}

// =====================================================================
// P1: stats for layer1 (Σy1, Σy1²). If ST, store raw y1 (pre-BN) bf16.
// Matmul inner loop packed as v2f -> v_pk_fma_f32 (2 f32/lane/instr).
// =====================================================================
template<bool ST>
__global__ __launch_bounds__(256) void pass1_kernel(
    const float* __restrict__ xyz, const float* __restrict__ points,
    const float* __restrict__ newxyz, const int* __restrict__ gidx,
    const float* __restrict__ w1, const float* __restrict__ b1,
    float* __restrict__ stats, unsigned short* __restrict__ y1bf) {
    __shared__ float featT[67 * LD];
    __shared__ float red[4][64], redq[4][64];
    const int tid = threadIdx.x, blk = blockIdx.x;
    stage64(xyz, points, newxyz, gidx, blk * 64, tid, featT);
    __syncthreads();
    const int c = tid & 63, rg = tid >> 6;
    float wr[67];
#pragma unroll
    for (int k = 0; k < 67; ++k) wr[k] = w1[c * 67 + k];
    const float bv = b1[c];
    v2f ssum2 = {0.f, 0.f}, ssq2 = {0.f, 0.f};
#pragma unroll
    for (int bat = 0; bat < 2; ++bat) {
        const int rb = rg * 16 + bat * 8;
        v2f acc2[4];
#pragma unroll
        for (int j = 0; j < 4; ++j) acc2[j] = (v2f){bv, bv};
#pragma unroll
        for (int k = 0; k < 67; ++k) {
            float f[8];
            *reinterpret_cast<float4*>(&f[0]) = *reinterpret_cast<const float4*>(&featT[k * LD + rb]);
            *reinterpret_cast<float4*>(&f[4]) = *reinterpret_cast<const float4*>(&featT[k * LD + rb + 4]);
            const v2f* fv = reinterpret_cast<const v2f*>(f);
            const v2f wv2 = {wr[k], wr[k]};
#pragma unroll
            for (int j = 0; j < 4; ++j) acc2[j] += fv[j] * wv2;
        }
        if (ST) {
            unsigned short o[8];
#pragma unroll
            for (int j = 0; j < 4; ++j) { o[2 * j] = f2bf(acc2[j].x); o[2 * j + 1] = f2bf(acc2[j].y); }
            *reinterpret_cast<uint4*>(&y1bf[(size_t)blk * 4096 + c * 64 + rb]) =
                *reinterpret_cast<uint4*>(o);
        }
#pragma unroll
        for (int j = 0; j < 4; ++j) { ssum2 += acc2[j]; ssq2 += acc2[j] * acc2[j]; }
    }
    red[rg][c] = ssum2.x + ssum2.y;
    redq[rg][c] = ssq2.x + ssq2.y;
    __syncthreads();
    if (tid < 64) {
        const float s = red[0][tid] + red[1][tid] + red[2][tid] + red[3][tid];
        const float q = redq[0][tid] + redq[1][tid] + redq[2][tid] + redq[3][tid];
        const int slot = blk & (NSLOT - 1);
        atomicAdd(&stats[S1SUM + slot * 64 + tid], s);
        atomicAdd(&stats[S1SQ + slot * 64 + tid], q);
    }
}

// =====================================================================
// P2big: load bf16 y1 tile, t1 = relu(bn1(y1)), y2 matmul (pk-f32),
// store y2 bf16 + stats2. No gather, no layer-1 recompute.
// =====================================================================
__global__ __launch_bounds__(256) void pass2big_kernel(
    const unsigned short* __restrict__ y1bf,
    const float* __restrict__ g1, const float* __restrict__ bt1,
    const float* __restrict__ w2, const float* __restrict__ b2,
    float* __restrict__ stats, unsigned short* __restrict__ y2bf) {
    __shared__ float t1T[64 * LD];
    __shared__ float a1s[64], c1s[64];
    __shared__ float red[4][64], redq[4][64];
    const int tid = threadIdx.x, blk = blockIdx.x;
    fold64(stats + S1SUM, stats + S1SQ, g1, bt1, tid, a1s, c1s);
    __syncthreads();
    {
        const int cch = tid >> 2, r0 = (tid & 3) * 16;
        const float a1 = a1s[cch], c1 = c1s[cch];
        const uint4 u0 = *reinterpret_cast<const uint4*>(&y1bf[(size_t)blk * 4096 + cch * 64 + r0]);
        const uint4 u1 = *reinterpret_cast<const uint4*>(&y1bf[(size_t)blk * 4096 + cch * 64 + r0 + 8]);
        const unsigned short* us0 = reinterpret_cast<const unsigned short*>(&u0);
        const unsigned short* us1 = reinterpret_cast<const unsigned short*>(&u1);
#pragma unroll
        for (int j = 0; j < 8; ++j) {
            t1T[cch * LD + r0 + j]     = fmaxf(0.f, fmaf(a1, bf2f(us0[j]), c1));
            t1T[cch * LD + r0 + 8 + j] = fmaxf(0.f, fmaf(a1, bf2f(us1[j]), c1));
        }
    }
    __syncthreads();
    const int c = tid & 63, rg = tid >> 6;
    float wr[64];
#pragma unroll
    for (int k = 0; k < 64; ++k) wr[k] = w2[c * 64 + k];
    const float bv = b2[c];
    v2f ssum2 = {0.f, 0.f}, ssq2 = {0.f, 0.f};
#pragma unroll
    for (int bat = 0; bat < 2; ++bat) {
        const int rb = rg * 16 + bat * 8;
        v2f acc2[4];
#pragma unroll
        for (int j = 0; j < 4; ++j) acc2[j] = (v2f){bv, bv};
#pragma unroll
        for (int k = 0; k < 64; ++k) {
            float f[8];
            *reinterpret_cast<float4*>(&f[0]) = *reinterpret_cast<const float4*>(&t1T[k * LD + rb]);
            *reinterpret_cast<float4*>(&f[4]) = *reinterpret_cast<const float4*>(&t1T[k * LD + rb + 4]);
            const v2f* fv = reinterpret_cast<const v2f*>(f);
            const v2f wv2 = {wr[k], wr[k]};
#pragma unroll
            for (int j = 0; j < 4; ++j) acc2[j] += fv[j] * wv2;
        }
        {
            unsigned short o[8];
#pragma unroll
            for (int j = 0; j < 4; ++j) { o[2 * j] = f2bf(acc2[j].x); o[2 * j + 1] = f2bf(acc2[j].y); }
            *reinterpret_cast<uint4*>(&y2bf[(size_t)blk * 4096 + c * 64 + rb]) =
                *reinterpret_cast<uint4*>(o);
        }
#pragma unroll
        for (int j = 0; j < 4; ++j) { ssum2 += acc2[j]; ssq2 += acc2[j] * acc2[j]; }
    }
    red[rg][c] = ssum2.x + ssum2.y;
    redq[rg][c] = ssq2.x + ssq2.y;
    __syncthreads();
    if (tid < 64) {
        const float s = red[0][tid] + red[1][tid] + red[2][tid] + red[3][tid];
        const float q = redq[0][tid] + redq[1][tid] + redq[2][tid] + redq[3][tid];
        const int slot = blk & (NSLOT - 1);
        atomicAdd(&stats[S2SUM + slot * 64 + tid], s);
        atomicAdd(&stats[S2SQ + slot * 64 + tid], q);
    }
}

// =====================================================================
// P2: full recompute variant (fallback). If ST stores y2 bf16.
// =====================================================================
template<bool ST>
__global__ __launch_bounds__(256) void pass2_kernel(
    const float* __restrict__ xyz, const float* __restrict__ points,
    const float* __restrict__ newxyz, const int* __restrict__ gidx,
    const float* __restrict__ w1, const float* __restrict__ b1,
    const float* __restrict__ g1, const float* __restrict__ bt1,
    const float* __restrict__ w2, const float* __restrict__ b2,
    float* __restrict__ stats, unsigned short* __restrict__ y2bf) {
    __shared__ float featT[67 * LD];
    __shared__ float t1T[64 * LD];
    __shared__ float a1s[64], c1s[64];
    __shared__ float red[4][64], redq[4][64];
    const int tid = threadIdx.x, blk = blockIdx.x;
    fold64(stats + S1SUM, stats + S1SQ, g1, bt1, tid, a1s, c1s);
    stage64(xyz, points, newxyz, gidx, blk * 64, tid, featT);
    __syncthreads();
    mm_bnrelu<67>(w1, b1, featT, t1T, a1s, c1s, tid);
    __syncthreads();
    const int c = tid & 63, rg = tid >> 6;
    float wr[64];
#pragma unroll
    for (int k = 0; k < 64; ++k) wr[k] = w2[c * 64 + k];
    const float bv = b2[c];
    float ssum = 0.f, ssq = 0.f;
#pragma unroll
    for (int bat = 0; bat < 2; ++bat) {
        const int rb = rg * 16 + bat * 8;
        float acc[8];
#pragma unroll
        for (int j = 0; j < 8; ++j) acc[j] = bv;
#pragma unroll
        for (int k = 0; k < 64; ++k) {
            float f[8];
            *reinterpret_cast<float4*>(&f[0]) = *reinterpret_cast<const float4*>(&t1T[k * LD + rb]);
            *reinterpret_cast<float4*>(&f[4]) = *reinterpret_cast<const float4*>(&t1T[k * LD + rb + 4]);
            const float wv = wr[k];
#pragma unroll
            for (int j = 0; j < 8; ++j) acc[j] = fmaf(f[j], wv, acc[j]);
        }
        if (ST) {
            unsigned short o[8];
#pragma unroll
            for (int j = 0; j < 8; ++j) o[j] = f2bf(acc[j]);
            *reinterpret_cast<uint4*>(&y2bf[(size_t)blk * 4096 + c * 64 + rb]) =
                *reinterpret_cast<uint4*>(o);
        }
#pragma unroll
        for (int j = 0; j < 8; ++j) { ssum += acc[j]; ssq = fmaf(acc[j], acc[j], ssq); }
    }
    red[rg][c] = ssum;
    redq[rg][c] = ssq;
    __syncthreads();
    if (tid < 64) {
        const float s = red[0][tid] + red[1][tid] + red[2][tid] + red[3][tid];
        const float q = redq[0][tid] + redq[1][tid] + redq[2][tid] + redq[3][tid];
        const int slot = blk & (NSLOT - 1);
        atomicAdd(&stats[S2SUM + slot * 64 + tid], s);
        atomicAdd(&stats[S2SQ + slot * 64 + tid], q);
    }
}

// =====================================================================
// P3big: load bf16 y2 tile, t2 = relu(bn2(y2)), y3 matmul (2-ch blocked,
// pk-f32), stats3 + per-(b,s,c) max/min.
// =====================================================================
__global__ __launch_bounds__(256) void pass3big_kernel(
    const unsigned short* __restrict__ y2bf,
    const float* __restrict__ g2, const float* __restrict__ bt2,
    const float* __restrict__ w3, const float* __restrict__ b3,
    float* __restrict__ stats, float* __restrict__ maxbuf, float* __restrict__ minbuf) {
    __shared__ float t2T[64 * LD];
    __shared__ float a2s[64], c2s[64];
    __shared__ float redM[4][128], redm[4][128], redS[4][128], redQ[4][128];
    const int tid = threadIdx.x, blk = blockIdx.x;
    fold64(stats + S2SUM, stats + S2SQ, g2, bt2, tid, a2s, c2s);
    __syncthreads();
    {
        const int cch = tid >> 2, r0 = (tid & 3) * 16;
        const float a2 = a2s[cch], c2 = c2s[cch];
        const uint4 u0 = *reinterpret_cast<const uint4*>(&y2bf[(size_t)blk * 4096 + cch * 64 + r0]);
        const uint4 u1 = *reinterpret_cast<const uint4*>(&y2bf[(size_t)blk * 4096 + cch * 64 + r0 + 8]);
        const unsigned short* us0 = reinterpret_cast<const unsigned short*>(&u0);
        const unsigned short* us1 = reinterpret_cast<const unsigned short*>(&u1);
#pragma unroll
        for (int j = 0; j < 8; ++j) {
            t2T[cch * LD + r0 + j]     = fmaxf(0.f, fmaf(a2, bf2f(us0[j]), c2));
            t2T[cch * LD + r0 + 8 + j] = fmaxf(0.f, fmaf(a2, bf2f(us1[j]), c2));
        }
    }
    __syncthreads();

    const int c0 = tid & 63, rg2 = tid >> 6;
    const int rb = rg2 * 16;
    v2f a0[8], a1[8];
    const float bv0 = b3[c0], bv1 = b3[c0 + 64];
#pragma unroll
    for (int j = 0; j < 8; ++j) { a0[j] = (v2f){bv0, bv0}; a1[j] = (v2f){bv1, bv1}; }
    for (int half = 0; half < 2; ++half) {
        float wr0[32], wr1[32];
#pragma unroll
        for (int k = 0; k < 32; ++k) {
            wr0[k] = w3[c0 * 64 + half * 32 + k];
            wr1[k] = w3[(c0 + 64) * 64 + half * 32 + k];
        }
#pragma unroll
        for (int k = 0; k < 32; ++k) {
            const int kk = half * 32 + k;
            float f[16];
            *reinterpret_cast<float4*>(&f[0])  = *reinterpret_cast<const float4*>(&t2T[kk * LD + rb]);
            *reinterpret_cast<float4*>(&f[4])  = *reinterpret_cast<const float4*>(&t2T[kk * LD + rb + 4]);
            *reinterpret_cast<float4*>(&f[8])  = *reinterpret_cast<const float4*>(&t2T[kk * LD + rb + 8]);
            *reinterpret_cast<float4*>(&f[12]) = *reinterpret_cast<const float4*>(&t2T[kk * LD + rb + 12]);
            const v2f* fv = reinterpret_cast<const v2f*>(f);
            const v2f w02 = {wr0[k], wr0[k]};
            const v2f w12 = {wr1[k], wr1[k]};
#pragma unroll
            for (int j = 0; j < 8; ++j) {
                a0[j] += fv[j] * w02;
                a1[j] += fv[j] * w12;
            }
        }
    }
    v2f mx0 = a0[0], mn0 = a0[0], mx1 = a1[0], mn1 = a1[0];
    v2f s0 = a0[0], q0 = a0[0] * a0[0], s1 = a1[0], q1 = a1[0] * a1[0];
#pragma unroll
    for (int j = 1; j < 8; ++j) {
        mx0 = __builtin_elementwise_max(mx0, a0[j]);
        mn0 = __builtin_elementwise_min(mn0, a0[j]);
        s0 += a0[j]; q0 += a0[j] * a0[j];
        mx1 = __builtin_elementwise_max(mx1, a1[j]);
        mn1 = __builtin_elementwise_min(mn1, a1[j]);
        s1 += a1[j]; q1 += a1[j] * a1[j];
    }
    redM[rg2][c0] = fmaxf(mx0.x, mx0.y); redM[rg2][c0 + 64] = fmaxf(mx1.x, mx1.y);
    redm[rg2][c0] = fminf(mn0.x, mn0.y); redm[rg2][c0 + 64] = fminf(mn1.x, mn1.y);
    redS[rg2][c0] = s0.x + s0.y;         redS[rg2][c0 + 64] = s1.x + s1.y;
    redQ[rg2][c0] = q0.x + q0.y;         redQ[rg2][c0 + 64] = q1.x + q1.y;
    __syncthreads();
    {
        const int g2i = tid >> 7, cc = tid & 127;
        const int g = blk * 2 + g2i;
        maxbuf[(size_t)g * 128 + cc] = fmaxf(redM[2 * g2i][cc], redM[2 * g2i + 1][cc]);
        minbuf[(size_t)g * 128 + cc] = fminf(redm[2 * g2i][cc], redm[2 * g2i + 1][cc]);
    }
    if (tid < 128) {
        const float s = (redS[0][tid] + redS[1][tid]) + (redS[2][tid] + redS[3][tid]);
        const float q = (redQ[0][tid] + redQ[1][tid]) + (redQ[2][tid] + redQ[3][tid]);
        const int slot = blk & (NSLOT - 1);
        atomicAdd(&stats[S3SUM + slot * 128 + tid], s);
        atomicAdd(&stats[S3SQ + slot * 128 + tid], q);
    }
}

// =====================================================================
// P3: full recompute variant (med/small ws). Stats3 + (MM) max/min.
// =====================================================================
template<bool MM>
__global__ __launch_bounds__(256) void pass3_kernel(
    const float* __restrict__ xyz, const float* __restrict__ points,
    const float* __restrict__ newxyz, const int* __restrict__ gidx,
    const float* __restrict__ w1, const float* __restrict__ b1,
    const float* __restrict__ g1, const float* __restrict__ bt1,
    const float* __restrict__ w2, const float* __restrict__ b2,
    const float* __restrict__ g2, const float* __restrict__ bt2,
    const float* __restrict__ w3, const float* __restrict__ b3,
    float* __restrict__ stats, float* __restrict__ maxbuf, float* __restrict__ minbuf) {
    __shared__ float bufA[67 * LD];
    __shared__ float t1T[64 * LD];
    __shared__ float a1s[64], c1s[64], a2s[64], c2s[64];
    __shared__ float redM[4][128], redm[4][128], redS[4][128], redQ[4][128];
    const int tid = threadIdx.x, blk = blockIdx.x;
    fold64(stats + S1SUM, stats + S1SQ, g1, bt1, tid, a1s, c1s);
    fold64(stats + S2SUM, stats + S2SQ, g2, bt2, tid, a2s, c2s);
    stage64(xyz, points, newxyz, gidx, blk * 64, tid, bufA);
    __syncthreads();
    mm_bnrelu<67>(w1, b1, bufA, t1T, a1s, c1s, tid);
    __syncthreads();
    mm_bnrelu<64>(w2, b2, t1T, bufA, a2s, c2s, tid);
    __syncthreads();

    const int c0 = tid & 63, rg2 = tid >> 6;
    const int rb = rg2 * 16;
    float acc0[16], acc1[16];
    const float bv0 = b3[c0], bv1 = b3[c0 + 64];
#pragma unroll
    for (int j = 0; j < 16; ++j) { acc0[j] = bv0; acc1[j] = bv1; }
    for (int half = 0; half < 2; ++half) {
        float wr0[32], wr1[32];
#pragma unroll
        for (int k = 0; k < 32; ++k) {
            wr0[k] = w3[c0 * 64 + half * 32 + k];
            wr1[k] = w3[(c0 + 64) * 64 + half * 32 + k];
        }
#pragma unroll
        for (int k = 0; k < 32; ++k) {
            const int kk = half * 32 + k;
            float f[16];
            *reinterpret_cast<float4*>(&f[0])  = *reinterpret_cast<const float4*>(&bufA[kk * LD + rb]);
            *reinterpret_cast<float4*>(&f[4])  = *reinterpret_cast<const float4*>(&bufA[kk * LD + rb + 4]);
            *reinterpret_cast<float4*>(&f[8])  = *reinterpret_cast<const float4*>(&bufA[kk * LD + rb + 8]);
            *reinterpret_cast<float4*>(&f[12]) = *reinterpret_cast<const float4*>(&bufA[kk * LD + rb + 12]);
            const float w0 = wr0[k], w1v = wr1[k];
#pragma unroll
            for (int j = 0; j < 16; ++j) {
                acc0[j] = fmaf(f[j], w0, acc0[j]);
                acc1[j] = fmaf(f[j], w1v, acc1[j]);
            }
        }
    }
    float maxv0 = -3.4e38f, minv0 = 3.4e38f, ssum0 = 0.f, ssq0 = 0.f;
    float maxv1 = -3.4e38f, minv1 = 3.4e38f, ssum1 = 0.f, ssq1 = 0.f;
#pragma unroll
    for (int j = 0; j < 16; ++j) {
        maxv0 = fmaxf(maxv0, acc0[j]); minv0 = fminf(minv0, acc0[j]);
        ssum0 += acc0[j]; ssq0 = fmaf(acc0[j], acc0[j], ssq0);
        maxv1 = fmaxf(maxv1, acc1[j]); minv1 = fminf(minv1, acc1[j]);
        ssum1 += acc1[j]; ssq1 = fmaf(acc1[j], acc1[j], ssq1);
    }
    redM[rg2][c0] = maxv0; redM[rg2][c0 + 64] = maxv1;
    redm[rg2][c0] = minv0; redm[rg2][c0 + 64] = minv1;
    redS[rg2][c0] = ssum0; redS[rg2][c0 + 64] = ssum1;
    redQ[rg2][c0] = ssq0;  redQ[rg2][c0 + 64] = ssq1;
    __syncthreads();
    if (MM) {
        const int g2i = tid >> 7, cc = tid & 127;
        const int g = blk * 2 + g2i;
        maxbuf[(size_t)g * 128 + cc] = fmaxf(redM[2 * g2i][cc], redM[2 * g2i + 1][cc]);
        minbuf[(size_t)g * 128 + cc] = fminf(redm[2 * g2i][cc], redm[2 * g2i + 1][cc]);
    }
    if (tid < 128) {
        const float s = (redS[0][tid] + redS[1][tid]) + (redS[2][tid] + redS[3][tid]);
        const float q = (redQ[0][tid] + redQ[1][tid]) + (redQ[2][tid] + redQ[3][tid]);
        const int slot = blk & (NSLOT - 1);
        atomicAdd(&stats[S3SUM + slot * 128 + tid], s);
        atomicAdd(&stats[S3SQ + slot * 128 + tid], q);
    }
}

// =====================================================================
// P4 (small-ws fallback): full recompute + BN3 + ReLU + maxpool -> out.
// =====================================================================
__global__ __launch_bounds__(256) void pass4_kernel(
    const float* __restrict__ xyz, const float* __restrict__ points,
    const float* __restrict__ newxyz, const int* __restrict__ gidx,
    const float* __restrict__ w1, const float* __restrict__ b1,
    const float* __restrict__ g1, const float* __restrict__ bt1,
    const float* __restrict__ w2, const float* __restrict__ b2,
    const float* __restrict__ g2, const float* __restrict__ bt2,
    const float* __restrict__ w3, const float* __restrict__ b3,
    const float* __restrict__ g3, const float* __restrict__ bt3,
    const float* __restrict__ stats, float* __restrict__ outp) {
    __shared__ float bufA[67 * LD];
    __shared__ float t1T[64 * LD];
    __shared__ float a1s[64], c1s[64], a2s[64], c2s[64];
    __shared__ float a3s[128], c3s[128];
    const int tid = threadIdx.x, blk = blockIdx.x;
    fold64(stats + S1SUM, stats + S1SQ, g1, bt1, tid, a1s, c1s);
    fold64(stats + S2SUM, stats + S2SQ, g2, bt2, tid, a2s, c2s);
    if (tid < 128) {
        float s = 0.f, q = 0.f;
#pragma unroll
        for (int sl = 0; sl < NSLOT; ++sl) { s += stats[S3SUM + sl * 128 + tid]; q += stats[S3SQ + sl * 128 + tid]; }
        const float Ninv = 1.0f / (float)NROWS;
        const float mean = s * Ninv;
        const float var  = fmaf(-mean, mean, q * Ninv);
        const float a    = g3[tid] * rsqrtf(var + BN_EPS);
        a3s[tid] = a;
        c3s[tid] = bt3[tid] - mean * a;
    }
    stage64(xyz, points, newxyz, gidx, blk * 64, tid, bufA);
    __syncthreads();
    mm_bnrelu<67>(w1, b1, bufA, t1T, a1s, c1s, tid);
    __syncthreads();
    mm_bnrelu<64>(w2, b2, t1T, bufA, a2s, c2s, tid);
    __syncthreads();

    const int c2 = tid & 127, rg2 = tid >> 7;
    float wr[64];
#pragma unroll
    for (int k = 0; k < 64; ++k) wr[k] = w3[c2 * 64 + k];
    const float bv = b3[c2];
    const float av = a3s[c2], cv = c3s[c2];
    float maxv = -3.4e38f;
#pragma unroll
    for (int bat = 0; bat < 4; ++bat) {
        const int rb = rg2 * 32 + bat * 8;
        float acc[8];
#pragma unroll
        for (int j = 0; j < 8; ++j) acc[j] = bv;
#pragma unroll
        for (int k = 0; k < 64; ++k) {
            float f[8];
            *reinterpret_cast<float4*>(&f[0]) = *reinterpret_cast<const float4*>(&bufA[k * LD + rb]);
            *reinterpret_cast<float4*>(&f[4]) = *reinterpret_cast<const float4*>(&bufA[k * LD + rb + 4]);
            const float wv = wr[k];
#pragma unroll
            for (int j = 0; j < 8; ++j) acc[j] = fmaf(f[j], wv, acc[j]);
        }
#pragma unroll
        for (int j = 0; j < 8; ++j) maxv = fmaxf(maxv, fmaxf(0.f, fmaf(av, acc[j], cv)));
    }
    const int g = blk * 2 + rg2;
    outp[(size_t)g * 128 + c2] = maxv;
}

// =====================================================================
// derive3 + final
// =====================================================================
__global__ void derive3_kernel(const float* __restrict__ g3, const float* __restrict__ bt3,
                               float* __restrict__ stats) {
    const int c = threadIdx.x;  // 128
    float s = 0.f, q = 0.f;
#pragma unroll
    for (int sl = 0; sl < NSLOT; ++sl) { s += stats[S3SUM + sl * 128 + c]; q += stats[S3SQ + sl * 128 + c]; }
    const float Ninv = 1.0f / (float)NROWS;
    const float mean = s * Ninv;
    const float var  = fmaf(-mean, mean, q * Ninv);
    const float a    = g3[c] * rsqrtf(var + BN_EPS);
    stats[A3OFF + c] = a;
    stats[C3OFF + c] = bt3[c] - mean * a;
}

__global__ __launch_bounds__(256) void final_kernel(
    const float* __restrict__ maxbuf, const float* __restrict__ minbuf,
    const float* __restrict__ stats, float* __restrict__ outp) {
    const int gid = blockIdx.x * 256 + threadIdx.x;
    if (gid >= NB * NPOINT * 128) return;
    const int c = gid & 127;
    const float a  = stats[A3OFF + c];
    const float cc = stats[C3OFF + c];
    const float v  = (a >= 0.f) ? maxbuf[gid] : minbuf[gid];
    outp[gid] = fmaxf(0.f, fmaf(a, v, cc));
}

// =====================================================================
extern "C" void kernel_launch(void* const* d_in, const int* in_sizes, int n_in,
                              void* d_out, int out_size, void* d_ws, size_t ws_size,
                              hipStream_t stream) {
    const float* xyz    = (const float*)d_in[0];
    const float* points = (const float*)d_in[1];
    const float* w1 = (const float*)d_in[2];
    const float* b1 = (const float*)d_in[3];
    const float* g1 = (const float*)d_in[4];
    const float* bt1 = (const float*)d_in[5];
    const float* w2 = (const float*)d_in[6];
    const float* b2 = (const float*)d_in[7];
    const float* g2 = (const float*)d_in[8];
    const float* bt2 = (const float*)d_in[9];
    const float* w3 = (const float*)d_in[10];
    const float* b3 = (const float*)d_in[11];
    const float* g3 = (const float*)d_in[12];
    const float* bt3 = (const float*)d_in[13];

    float* out_newxyz = (float*)d_out;
    float* out_newpts = (float*)d_out + NB * NPOINT * 3;

    char* ws = (char*)d_ws;
    if (ws_size < SMALL_TOTAL) return;  // cannot run at all

    int*   gidx   = (int*)(ws + OFF_GIDX);
    float* stats  = (float*)(ws + OFF_STATS);
    float* maxbuf = (float*)(ws + OFF_MAX);
    float* minbuf = (float*)(ws + OFF_MIN);
    unsigned short* y2bf = (unsigned short*)(ws + OFF_Y2BF);
    unsigned short* y1bf = (unsigned short*)(ws + OFF_Y1BF);
    const bool med  = (ws_size >= MED_TOTAL);
    const bool big  = (ws_size >= BIG_TOTAL);
    const bool big2 = (ws_size >= BIG2_TOTAL);

    hipMemsetAsync(stats, 0, 65536, stream);

    fps_kernel<<<NB, 256, 0, stream>>>(xyz, out_newxyz);
    query_kernel<<<(NB * NPOINT * 64) / 256, 256, 0, stream>>>(xyz, out_newxyz, gidx);
    if (big2) {
        pass1_kernel<true><<<NROWS / 64, 256, 0, stream>>>(xyz, points, out_newxyz, gidx,
                                                           w1, b1, stats, y1bf);
        pass2big_kernel<<<NROWS / 64, 256, 0, stream>>>(y1bf, g1, bt1, w2, b2, stats, y2bf);
        pass3big_kernel<<<NROWS / 64, 256, 0, stream>>>(y2bf, g2, bt2, w3, b3,
                                                        stats, maxbuf, minbuf);
        derive3_kernel<<<1, 128, 0, stream>>>(g3, bt3, stats);
        final_kernel<<<(NB * NPOINT * 128) / 256, 256, 0, stream>>>(maxbuf, minbuf, stats, out_newpts);
    } else if (big) {
        pass1_kernel<false><<<NROWS / 64, 256, 0, stream>>>(xyz, points, out_newxyz, gidx,
                                                            w1, b1, stats, y1bf);
        pass2_kernel<true><<<NROWS / 64, 256, 0, stream>>>(xyz, points, out_newxyz, gidx,
                                                           w1, b1, g1, bt1, w2, b2, stats, y2bf);
        pass3big_kernel<<<NROWS / 64, 256, 0, stream>>>(y2bf, g2, bt2, w3, b3,
                                                        stats, maxbuf, minbuf);
        derive3_kernel<<<1, 128, 0, stream>>>(g3, bt3, stats);
        final_kernel<<<(NB * NPOINT * 128) / 256, 256, 0, stream>>>(maxbuf, minbuf, stats, out_newpts);
    } else if (med) {
        pass1_kernel<false><<<NROWS / 64, 256, 0, stream>>>(xyz, points, out_newxyz, gidx,
                                                            w1, b1, stats, y1bf);
        pass2_kernel<false><<<NROWS / 64, 256, 0, stream>>>(xyz, points, out_newxyz, gidx,
                                                            w1, b1, g1, bt1, w2, b2, stats, y2bf);
        pass3_kernel<true><<<NROWS / 64, 256, 0, stream>>>(xyz, points, out_newxyz, gidx,
                                                           w1, b1, g1, bt1, w2, b2, g2, bt2,
                                                           w3, b3, stats, maxbuf, minbuf);
        derive3_kernel<<<1, 128, 0, stream>>>(g3, bt3, stats);
        final_kernel<<<(NB * NPOINT * 128) / 256, 256, 0, stream>>>(maxbuf, minbuf, stats, out_newpts);
    } else {
        pass1_kernel<false><<<NROWS / 64, 256, 0, stream>>>(xyz, points, out_newxyz, gidx,
                                                            w1, b1, stats, y1bf);
        pass2_kernel<false><<<NROWS / 64, 256, 0, stream>>>(xyz, points, out_newxyz, gidx,
                                                            w1, b1, g1, bt1, w2, b2, stats, y2bf);
        pass3_kernel<false><<<NROWS / 64, 256, 0, stream>>>(xyz, points, out_newxyz, gidx,
                                                            w1, b1, g1, bt1, w2, b2, g2, bt2,
                                                            w3, b3, stats, maxbuf, minbuf);
        pass4_kernel<<<NROWS / 64, 256, 0, stream>>>(xyz, points, out_newxyz, gidx,
                                                     w1, b1, g1, bt1, w2, b2, g2, bt2,
                                                     w3, b3, g3, bt3, stats, out_newpts);
    }
}